// Round 1
// baseline (374.754 us; speedup 1.0000x reference)
//
#include <hip/hip_runtime.h>
#include <math.h>

// Problem constants (fixed by the reference)
constexpr int Bb  = 2;
constexpr int Ss  = 2048;
constexpr int Dd  = 2048;
constexpr int Hh  = 16;
constexpr int DHd = 128;
constexpr int BS  = Bb * Ss;   // 4096
constexpr int NQKV = 2304;     // 2048 q + 128 k + 128 v

typedef __bf16 bf16x8 __attribute__((ext_vector_type(8)));
typedef float  f32x4  __attribute__((ext_vector_type(4)));

// fp32 -> bf16 (RNE), bit-level
static __device__ __forceinline__ unsigned short f2bf(float f) {
  union { float f; unsigned int u; } a; a.f = f;
  unsigned int u = a.u;
  unsigned int r = (u + 0x7fffu + ((u >> 16) & 1u)) >> 16;
  return (unsigned short)r;
}
static __device__ __forceinline__ float bf2f(unsigned short u) {
  union { unsigned int u; float f; } a; a.u = ((unsigned int)u) << 16;
  return a.f;
}
// pack two fp32 -> one dword of 2 bf16 (lo = first)
static __device__ __forceinline__ int pk2bf(float lo, float hi) {
  return (int)((unsigned int)f2bf(lo) | ((unsigned int)f2bf(hi) << 16));
}
static __device__ __forceinline__ f32x4 mfma16(bf16x8 a, bf16x8 b, f32x4 c) {
  return __builtin_amdgcn_mfma_f32_16x16x32_bf16(a, b, c, 0, 0, 0);
}

// ---------------------------------------------------------------------------
// cast ALL fp32 inputs -> bf16 into one contiguous ws region:
//   [qw (2048x2048) | kvw (256x2048) | ow (2048x2048) | x (4096x2048)]
// ---------------------------------------------------------------------------
__global__ __launch_bounds__(256) void cast_all(
    const float* __restrict__ qw, const float* __restrict__ kvw,
    const float* __restrict__ ow, const float* __restrict__ x,
    unsigned short* __restrict__ dst)
{
  const int i = blockIdx.x * 256 + threadIdx.x;   // grid sized exactly
  const float* src; int off;
  if (i < 1048576)      { src = qw;  off = 0; }
  else if (i < 1179648) { src = kvw; off = 1048576; }
  else if (i < 2228224) { src = ow;  off = 1179648; }
  else                  { src = x;   off = 2228224; }
  const float4 v = ((const float4*)src)[i - off];
  ushort4 o;
  o.x = f2bf(v.x); o.y = f2bf(v.y); o.z = f2bf(v.z); o.w = f2bf(v.w);
  ((ushort4*)dst)[i] = o;
}

// ---------------------------------------------------------------------------
// bf16 MFMA GEMM: C[M][N] = A[M][K] @ Bw[N][K]^T + bias(col).
// bias(col) = col < nsplit ? bias1[col] : bias2[col-nsplit]  (merged QKV).
// 128x128 tile, BK=32, 256 threads, global_load_lds width-16 staging.
// ---------------------------------------------------------------------------
#define TM 128
#define TN 128
#define TK 32

#define GLOAD16(gp, lp)                                                        \
  __builtin_amdgcn_global_load_lds(                                            \
      (const __attribute__((address_space(1))) void*)(gp),                     \
      (__attribute__((address_space(3))) void*)(lp), 16, 0, 0)

template <bool BF16OUT>
__global__ __launch_bounds__(256) void gemm_bt_mfma(
    const unsigned short* __restrict__ A,    // M x K bf16
    const unsigned short* __restrict__ Bw,   // N x K bf16
    const float* __restrict__ bias1,
    const float* __restrict__ bias2,
    int nsplit,
    void* __restrict__ Cv,                   // M x N (fp32 or bf16)
    int M, int N, int K)
{
  __shared__ unsigned short As[TM * TK];   // 8 KB
  __shared__ unsigned short Bs[TN * TK];   // 8 KB

  const int tid  = threadIdx.x;
  const int w    = tid >> 6;
  const int lane = tid & 63;
  const int m0   = blockIdx.y * TM;
  const int n0   = blockIdx.x * TN;
  const int wm   = (w >> 1) * 64;
  const int wn   = (w & 1) * 64;

  f32x4 acc[4][4];
#pragma unroll
  for (int i = 0; i < 4; i++)
#pragma unroll
    for (int j = 0; j < 4; j++) acc[i][j] = (f32x4){0.f, 0.f, 0.f, 0.f};

  const int srow = lane >> 2;
  const int scol = (lane & 3) * 8;
  const unsigned short* aG0 = A  + (size_t)(m0 +      w * 16 + srow) * K + scol;
  const unsigned short* aG1 = A  + (size_t)(m0 + 64 + w * 16 + srow) * K + scol;
  const unsigned short* bG0 = Bw + (size_t)(n0 +      w * 16 + srow) * K + scol;
  const unsigned short* bG1 = Bw + (size_t)(n0 + 64 + w * 16 + srow) * K + scol;
  unsigned short* aL0 = &As[(     w * 16) * TK];
  unsigned short* aL1 = &As[(64 + w * 16) * TK];
  unsigned short* bL0 = &Bs[(     w * 16) * TK];
  unsigned short* bL1 = &Bs[(64 + w * 16) * TK];

  const int fr = lane & 15;
  const int fk = (lane >> 4) * 8;

  for (int k0 = 0; k0 < K; k0 += TK) {
    __syncthreads();
    GLOAD16(aG0 + k0, aL0);
    GLOAD16(aG1 + k0, aL1);
    GLOAD16(bG0 + k0, bL0);
    GLOAD16(bG1 + k0, bL1);
    __syncthreads();

    bf16x8 af[4], bfr[4];
#pragma unroll
    for (int i = 0; i < 4; i++)
      af[i] = *(const bf16x8*)&As[(wm + i * 16 + fr) * TK + fk];
#pragma unroll
    for (int j = 0; j < 4; j++)
      bfr[j] = *(const bf16x8*)&Bs[(wn + j * 16 + fr) * TK + fk];
#pragma unroll
    for (int i = 0; i < 4; i++)
#pragma unroll
      for (int j = 0; j < 4; j++)
        acc[i][j] = mfma16(af[i], bfr[j], acc[i][j]);
  }

  const int er = (lane >> 4) * 4;
  const int ec = lane & 15;
#pragma unroll
  for (int j = 0; j < 4; j++) {
    const int col = n0 + wn + j * 16 + ec;
    const float bv = (col < nsplit) ? bias1[col] : bias2[col - nsplit];
#pragma unroll
    for (int i = 0; i < 4; i++) {
      const int rbase = m0 + wm + i * 16 + er;
#pragma unroll
      for (int r = 0; r < 4; r++) {
        const float v = acc[i][j][r] + bv;
        if constexpr (BF16OUT)
          ((unsigned short*)Cv)[(size_t)(rbase + r) * N + col] = f2bf(v);
        else
          ((float*)Cv)[(size_t)(rbase + r) * N + col] = v;
      }
    }
  }
}

// ---------------------------------------------------------------------------
// RoPE in-place on q columns of QKV bf16 (B,S,2304).
// ---------------------------------------------------------------------------
__global__ __launch_bounds__(256) void rope_q_bf16(unsigned short* __restrict__ QKV)
{
  const int row = blockIdx.x;        // b*S + s
  const int s   = row & (Ss - 1);
  const int t   = threadIdx.x;
  const int h   = t >> 4, p = t & 15;
  unsigned short* base = QKV + (size_t)row * NQKV + h * DHd + p * 4;

  union { ushort4 v; unsigned short a[4]; } lo, hi, olo, ohi;
  lo.v = *(ushort4*)base;
  hi.v = *(ushort4*)(base + 64);
#pragma unroll
  for (int d = 0; d < 4; d++) {
    const int i = p * 4 + d;
    const float invf = exp2f(-(float)i * (13.287712379549449f / 64.0f)); // 10000^(-i/64)
    const float ang = (float)s * invf;
    const float c = cosf(ang), sn = sinf(ang);
    const float l = bf2f(lo.a[d]), hh = bf2f(hi.a[d]);
    olo.a[d] = f2bf(l * c - hh * sn);
    ohi.a[d] = f2bf(hh * c + l * sn);
  }
  *(ushort4*)base        = olo.v;
  *(ushort4*)(base + 64) = ohi.v;
}

// ---------------------------------------------------------------------------
// prep_kv: from QKV bf16 (B,S,2304) — k cols [2048,2176), v cols [2176,2304) —
// produce Kb (B,S,128) roped and Vt (B,128,S) transposed.
// ---------------------------------------------------------------------------
__global__ __launch_bounds__(256) void prep_kv(
    const unsigned short* __restrict__ QKV,
    unsigned short* __restrict__ Kb,
    unsigned short* __restrict__ Vt)
{
  __shared__ unsigned short Vtile[64 * 136];   // [s_local][d], padded

  const int blk = blockIdx.x;          // b*32 + stile
  const int b   = blk >> 5;
  const int s0  = (blk & 31) * 64;
  const int t   = threadIdx.x;

  // --- rope K
  {
    const int r = t >> 2, p = t & 3;
    const int row = blk * 64 + r;
    const int s = row & (Ss - 1);
    const unsigned short* src = QKV + (size_t)row * NQKV + 2048 + p * 16;
    union { uint4 v[2]; unsigned short a[16]; } lo, hi, ol, oh;
    lo.v[0] = *(const uint4*)src;        lo.v[1] = *(const uint4*)(src + 8);
    hi.v[0] = *(const uint4*)(src + 64); hi.v[1] = *(const uint4*)(src + 72);
#pragma unroll
    for (int e = 0; e < 16; e++) {
      const int i = p * 16 + e;
      const float invf = exp2f(-(float)i * (13.287712379549449f / 64.0f));
      const float ang = (float)s * invf;
      const float c = cosf(ang), sn = sinf(ang);
      const float l = bf2f(lo.a[e]), hh = bf2f(hi.a[e]);
      ol.a[e] = f2bf(l * c - hh * sn);
      oh.a[e] = f2bf(hh * c + l * sn);
    }
    unsigned short* dst = Kb + (size_t)row * 128 + p * 16;
    *(uint4*)dst        = ol.v[0]; *(uint4*)(dst + 8)  = ol.v[1];
    *(uint4*)(dst + 64) = oh.v[0]; *(uint4*)(dst + 72) = oh.v[1];
  }

  // --- stage V into LDS, s-major
#pragma unroll
  for (int c = 0; c < 4; c++) {
    const int id = c * 256 + t;
    const int vr = id >> 4, cc = id & 15;
    *(uint4*)&Vtile[vr * 136 + cc * 8] =
        *(const uint4*)(QKV + (size_t)(blk * 64 + vr) * NQKV + 2176 + cc * 8);
  }
  __syncthreads();

  // --- write Vt rows
  {
    const int d = t >> 1, half = t & 1;
    union { uint4 v[4]; unsigned short a[32]; } val;
#pragma unroll
    for (int kk = 0; kk < 32; kk++)
      val.a[kk] = Vtile[(half * 32 + kk) * 136 + d];
    unsigned short* dst = Vt + ((size_t)(b * 128 + d)) * Ss + s0 + half * 32;
#pragma unroll
    for (int c = 0; c < 4; c++) *(uint4*)(dst + c * 8) = val.v[c];
  }
}

// ---------------------------------------------------------------------------
// flash_v6: causal MQA attention, double-buffered staging (T3 minimum-2-phase).
// Grid (S/64, H, B) = 1024 blocks, 256 threads = 4 waves; wave w owns q-rows
// q0+w*16..+15 (q-split: no cross-wave combine).
// LDS per buffer: K in 4 dh-panels [64 keys x 32 dh] (64B rows), V in 2
// key-panels [128 dh x 32 keys] (64B rows); 2 buffers (64 KB total).
// Iteration: barrier (drains prev-issued stage of buf[cur]) -> issue stage of
// buf[cur^1] for tile t+1 -> compute from buf[cur]. One barrier per tile; the
// staging L2 latency hides under the previous tile's LDS reads + MFMAs.
// S^T = K·Q^T; p=exp2(s*scale) (max-free); P^T C->B layout via 8 bpermutes;
// O^T = V^T·P^T.
// ---------------------------------------------------------------------------
__global__ __launch_bounds__(256, 2) void flash_v6(
    const unsigned short* __restrict__ QKV,  // (B,S,2304), q roped in [0,2048)
    const unsigned short* __restrict__ Kb,   // (B,S,128) roped
    const unsigned short* __restrict__ Vt,   // (B,128,S)
    unsigned short* __restrict__ attn)       // (B,S,2048) bf16
{
  __shared__ unsigned short Ks[2][4 * 64 * 32];   // 2 x 16 KB
  __shared__ unsigned short Vs[2][2 * 128 * 32];  // 2 x 16 KB

  const int qt = 31 - (int)blockIdx.x;         // heavy tiles first
  const int h = blockIdx.y, b = blockIdx.z;
  const int q0 = qt * 64;
  const int tid = threadIdx.x;
  const int w = tid >> 6, lane = tid & 63;
  const int lg = lane >> 4, lm = lane & 15;
  const int qrow = q0 + w * 16 + lm;           // this lane's q-row
  const int qrow_hi = q0 + w * 16 + 15;        // wave's last q-row

  // Q as B-operand frags: [kf]: lane: n=qrow(lm), k = kf*32 + lg*8 + j (dh)
  bf16x8 qf[4];
  {
    const unsigned short* qp =
        QKV + (size_t)(b * Ss + qrow) * NQKV + h * DHd + lg * 8;
#pragma unroll
    for (int kf = 0; kf < 4; kf++) qf[kf] = *(const bf16x8*)(qp + kf * 32);
  }

  // O^T accumulator, C-layout: element (dh = dt*16 + 4*lg + r, qrow = lm)
  f32x4 ot[8];
#pragma unroll
  for (int dt = 0; dt < 8; dt++) ot[dt] = (f32x4){0.f, 0.f, 0.f, 0.f};
  float lsum = 0.f;

  const float sscale = 0.08838834764831845f * 1.4426950408889634f; // /sqrt(128)*log2e

  // staging lane addresses
  const int sr  = lane >> 2;          // row-within-16
  const int sc8 = (lane & 3) * 8;     // 16B chunk
  const unsigned short* kg =
      Kb + (size_t)b * Ss * 128 + (size_t)sr * 128 + w * 32 + sc8;
  const unsigned short* vg =
      Vt + (size_t)b * 128 * Ss + (size_t)(w * 32 + sr) * Ss + sc8;

  // issue the 8 global_load_lds for key-tile j0 into buffer bi (per wave:
  // K panel w = dh w*32..+31 for 64 keys; V dh-rows w*32..+31, both 32-key
  // panels)
  auto stage = [&](int bi, int j0) {
    unsigned short* ksl  = &Ks[bi][w * 2048];
    unsigned short* vsl0 = &Vs[bi][(w * 32) * 32];
    unsigned short* vsl1 = &Vs[bi][4096 + (w * 32) * 32];
#pragma unroll
    for (int i = 0; i < 4; i++)
      GLOAD16(kg + (size_t)(j0 + i * 16) * 128, ksl + i * 512);
#pragma unroll
    for (int i = 0; i < 2; i++) {
      GLOAD16(vg + (size_t)(i * 16) * Ss + j0,      vsl0 + i * 512);
      GLOAD16(vg + (size_t)(i * 16) * Ss + j0 + 32, vsl1 + i * 512);
    }
  };

  // transpose shuffle sources (C->B layout, within a 32-key half)
  const int addr0 = (2 * (lg & 1)) * 16 + lm;   // dwords 0,1
  const int addr1 = addr0 + 16;                 // dwords 2,3
  const bool sel_hi = (lg & 2) != 0;

  // one 32-key half: S^T tiles tA,tA+1 -> exp -> transpose -> PV on panel VsP
  auto half32 = [&](int keybase, int tA, const unsigned short* KsP,
                    const unsigned short* VsP) {
    f32x4 s[2];
    s[0] = (f32x4){0.f, 0.f, 0.f, 0.f};
    s[1] = (f32x4){0.f, 0.f, 0.f, 0.f};
#pragma unroll
    for (int kf = 0; kf < 4; kf++) {
      const bf16x8 k0 = *(const bf16x8*)&KsP[kf * 2048 + ((tA)     * 16 + lm) * 32 + lg * 8];
      const bf16x8 k1 = *(const bf16x8*)&KsP[kf * 2048 + ((tA + 1) * 16 + lm) * 32 + lg * 8];
      s[0] = mfma16(k0, qf[kf], s[0]);
      s[1] = mfma16(k1, qf[kf], s[1]);
    }
    // mask + exp2 (max-free) + pack
    int pk[2][2];
#pragma unroll
    for (int t = 0; t < 2; t++) {
      float p[4];
#pragma unroll
      for (int r = 0; r < 4; r++) {
        const int key = keybase + t * 16 + 4 * lg + r;
        const float ev = exp2f(s[t][r] * sscale);
        p[r] = (key <= qrow) ? ev : 0.f;
        lsum += p[r];
      }
      pk[t][0] = pk2bf(p[0], p[1]);
      pk[t][1] = pk2bf(p[2], p[3]);
    }
    // C-layout -> B-layout transpose (8 bpermutes)
    union { int d[4]; bf16x8 v; } pb;
#pragma unroll
    for (int d = 0; d < 4; d++) {
      const int src = (d < 2) ? addr0 : addr1;
      const int v0 = __shfl(pk[0][d & 1], src);
      const int v1 = __shfl(pk[1][d & 1], src);
      pb.d[d] = sel_hi ? v1 : v0;
    }
    // O^T += V^T(32 keys) · P^T
#pragma unroll
    for (int dt = 0; dt < 8; dt++) {
      const bf16x8 vfrag = *(const bf16x8*)&VsP[(dt * 16 + lm) * 32 + lg * 8];
      ot[dt] = mfma16(vfrag, pb.v, ot[dt]);
    }
  };

  // prologue: stage first tile into buffer 0
  stage(0, 0);
  int cur = 0;

  for (int j0 = 0; j0 <= q0; j0 += 64) {
    // drains buf[cur]'s staging (issued last iter, overlapped with compute)
    // and guarantees all waves finished reading buf[cur^1]
    __syncthreads();
    if (j0 + 64 <= q0) stage(cur ^ 1, j0 + 64);   // issue next tile's loads

    const unsigned short* KsP = &Ks[cur][0];
    half32(j0, 0, KsP, &Vs[cur][0]);              // keys j0..j0+31
    if (j0 + 32 <= qrow_hi)                       // wave-uniform skip
      half32(j0 + 32, 2, KsP, &Vs[cur][4096]);    // keys j0+32..j0+63
    cur ^= 1;
  }

  // reduce lsum over the 4 lg groups (same lm = same qrow)
  lsum += __shfl_xor(lsum, 16);
  lsum += __shfl_xor(lsum, 32);
  const float inv = 1.0f / lsum;

  // store: lane covers (qrow, dh = dt*16 + 4lg + 0..3)
  unsigned short* dst = attn + (size_t)(b * Ss + qrow) * Dd + h * DHd + lg * 4;
#pragma unroll
  for (int dt = 0; dt < 8; dt++) {
    ushort4 o4;
    o4.x = f2bf(ot[dt][0] * inv);
    o4.y = f2bf(ot[dt][1] * inv);
    o4.z = f2bf(ot[dt][2] * inv);
    o4.w = f2bf(ot[dt][3] * inv);
    *(ushort4*)(dst + dt * 16) = o4;
  }
}

// ---------------------------------------------------------------------------
extern "C" void kernel_launch(void* const* d_in, const int* in_sizes, int n_in,
                              void* d_out, int out_size, void* d_ws, size_t ws_size,
                              hipStream_t stream) {
  const float* x   = (const float*)d_in[0];   // (B,S,D)
  const float* qw  = (const float*)d_in[1];   // (2048, 2048)
  const float* qb  = (const float*)d_in[2];
  const float* kvw = (const float*)d_in[3];   // (256, 2048)
  const float* kvb = (const float*)d_in[4];
  const float* ow  = (const float*)d_in[5];   // (2048, 2048)
  const float* ob  = (const float*)d_in[6];
  float* out = (float*)d_out;

  // workspace layout (bf16 elements):
  //   wqkv @ 0          (2304 x 2048)   qw rows 0-2047, kvw 2048-2303
  //   owb  @ 4,718,592  (2048 x 2048)
  //   xb   @ 8,912,896  (4096 x 2048)   -> reused as attn_b
  //   QKV  @ 17,301,504 (4096 x 2304)
  //   Kb   @ 26,738,688 (4096 x 128)
  //   Vt   @ 27,262,976 (2 x 128 x 2048)
  unsigned short* wsb    = (unsigned short*)d_ws;
  unsigned short* wqkv   = wsb;
  unsigned short* owb    = wsb + 4718592;
  unsigned short* xb     = wsb + 8912896;
  unsigned short* attn_b = xb;                 // alias: xb dead after QKV gemm
  unsigned short* QKV    = wsb + 17301504;
  unsigned short* Kb     = wsb + 26738688;
  unsigned short* Vt     = wsb + 27262976;

  // 1. all fp32->bf16 casts in one kernel
  cast_all<<<16896, 256, 0, stream>>>(qw, kvw, ow, x, wqkv);

  // 2. merged QKV projection: (4096 x 2304) = xb @ wqkv^T + [qb|kvb]
  gemm_bt_mfma<true><<<dim3(NQKV / TN, BS / TM), 256, 0, stream>>>(
      xb, wqkv, qb, kvb, 2048, QKV, BS, NQKV, Dd);

  // 3. RoPE q in-place; 4. K rope + V transpose
  rope_q_bf16<<<BS, 256, 0, stream>>>(QKV);
  prep_kv<<<BS / 64, 256, 0, stream>>>(QKV, Kb, Vt);

  // 5. flash attention (double-buffered staging)
  flash_v6<<<dim3(Ss / 64, Hh, Bb), 256, 0, stream>>>(QKV, Kb, Vt, attn_b);

  // 6. O projection: out = attn @ ow^T + ob (fp32 out)
  gemm_bt_mfma<false><<<dim3(Dd / TN, BS / TM), 256, 0, stream>>>(
      attn_b, owb, ob, ob, Dd, out, BS, Dd, Dd);
}

// Round 2
// 324.380 us; speedup vs baseline: 1.1553x; 1.1553x over previous
//
#include <hip/hip_runtime.h>
#include <math.h>

// Problem constants (fixed by the reference)
constexpr int Bb  = 2;
constexpr int Ss  = 2048;
constexpr int Dd  = 2048;
constexpr int Hh  = 16;
constexpr int DHd = 128;
constexpr int BS  = Bb * Ss;   // 4096
constexpr int NQKV = 2304;     // 2048 q + 128 k + 128 v

typedef __bf16 bf16x8 __attribute__((ext_vector_type(8)));
typedef float  f32x4  __attribute__((ext_vector_type(4)));

// fp32 -> bf16 (RNE), bit-level
static __device__ __forceinline__ unsigned short f2bf(float f) {
  union { float f; unsigned int u; } a; a.f = f;
  unsigned int u = a.u;
  unsigned int r = (u + 0x7fffu + ((u >> 16) & 1u)) >> 16;
  return (unsigned short)r;
}
static __device__ __forceinline__ float bf2f(unsigned short u) {
  union { unsigned int u; float f; } a; a.u = ((unsigned int)u) << 16;
  return a.f;
}
// pack two fp32 -> one dword of 2 bf16 (lo = first)
static __device__ __forceinline__ int pk2bf(float lo, float hi) {
  return (int)((unsigned int)f2bf(lo) | ((unsigned int)f2bf(hi) << 16));
}
static __device__ __forceinline__ f32x4 mfma16(bf16x8 a, bf16x8 b, f32x4 c) {
  return __builtin_amdgcn_mfma_f32_16x16x32_bf16(a, b, c, 0, 0, 0);
}

// ---------------------------------------------------------------------------
// cast ALL fp32 inputs -> bf16 into one contiguous ws region:
//   [qw (2048x2048) | kvw (256x2048) | ow (2048x2048) | x (4096x2048)]
// ---------------------------------------------------------------------------
__global__ __launch_bounds__(256) void cast_all(
    const float* __restrict__ qw, const float* __restrict__ kvw,
    const float* __restrict__ ow, const float* __restrict__ x,
    unsigned short* __restrict__ dst)
{
  const int i = blockIdx.x * 256 + threadIdx.x;   // grid sized exactly
  const float* src; int off;
  if (i < 1048576)      { src = qw;  off = 0; }
  else if (i < 1179648) { src = kvw; off = 1048576; }
  else if (i < 2228224) { src = ow;  off = 1179648; }
  else                  { src = x;   off = 2228224; }
  const float4 v = ((const float4*)src)[i - off];
  ushort4 o;
  o.x = f2bf(v.x); o.y = f2bf(v.y); o.z = f2bf(v.z); o.w = f2bf(v.w);
  ((ushort4*)dst)[i] = o;
}

// ---------------------------------------------------------------------------
// bf16 MFMA GEMM: C[M][N] = A[M][K] @ Bw[N][K]^T + bias(col).
// bias(col) = col < nsplit ? bias1[col] : bias2[col-nsplit]  (merged QKV).
// 128x128 tile, BK=32, 256 threads, global_load_lds width-16 staging.
// ---------------------------------------------------------------------------
#define TM 128
#define TN 128
#define TK 32

#define GLOAD16(gp, lp)                                                        \
  __builtin_amdgcn_global_load_lds(                                            \
      (const __attribute__((address_space(1))) void*)(gp),                     \
      (__attribute__((address_space(3))) void*)(lp), 16, 0, 0)

template <bool BF16OUT>
__global__ __launch_bounds__(256) void gemm_bt_mfma(
    const unsigned short* __restrict__ A,    // M x K bf16
    const unsigned short* __restrict__ Bw,   // N x K bf16
    const float* __restrict__ bias1,
    const float* __restrict__ bias2,
    int nsplit,
    void* __restrict__ Cv,                   // M x N (fp32 or bf16)
    int M, int N, int K)
{
  __shared__ unsigned short As[TM * TK];   // 8 KB
  __shared__ unsigned short Bs[TN * TK];   // 8 KB

  const int tid  = threadIdx.x;
  const int w    = tid >> 6;
  const int lane = tid & 63;
  const int m0   = blockIdx.y * TM;
  const int n0   = blockIdx.x * TN;
  const int wm   = (w >> 1) * 64;
  const int wn   = (w & 1) * 64;

  f32x4 acc[4][4];
#pragma unroll
  for (int i = 0; i < 4; i++)
#pragma unroll
    for (int j = 0; j < 4; j++) acc[i][j] = (f32x4){0.f, 0.f, 0.f, 0.f};

  const int srow = lane >> 2;
  const int scol = (lane & 3) * 8;
  const unsigned short* aG0 = A  + (size_t)(m0 +      w * 16 + srow) * K + scol;
  const unsigned short* aG1 = A  + (size_t)(m0 + 64 + w * 16 + srow) * K + scol;
  const unsigned short* bG0 = Bw + (size_t)(n0 +      w * 16 + srow) * K + scol;
  const unsigned short* bG1 = Bw + (size_t)(n0 + 64 + w * 16 + srow) * K + scol;
  unsigned short* aL0 = &As[(     w * 16) * TK];
  unsigned short* aL1 = &As[(64 + w * 16) * TK];
  unsigned short* bL0 = &Bs[(     w * 16) * TK];
  unsigned short* bL1 = &Bs[(64 + w * 16) * TK];

  const int fr = lane & 15;
  const int fk = (lane >> 4) * 8;

  for (int k0 = 0; k0 < K; k0 += TK) {
    __syncthreads();
    GLOAD16(aG0 + k0, aL0);
    GLOAD16(aG1 + k0, aL1);
    GLOAD16(bG0 + k0, bL0);
    GLOAD16(bG1 + k0, bL1);
    __syncthreads();

    bf16x8 af[4], bfr[4];
#pragma unroll
    for (int i = 0; i < 4; i++)
      af[i] = *(const bf16x8*)&As[(wm + i * 16 + fr) * TK + fk];
#pragma unroll
    for (int j = 0; j < 4; j++)
      bfr[j] = *(const bf16x8*)&Bs[(wn + j * 16 + fr) * TK + fk];
#pragma unroll
    for (int i = 0; i < 4; i++)
#pragma unroll
      for (int j = 0; j < 4; j++)
        acc[i][j] = mfma16(af[i], bfr[j], acc[i][j]);
  }

  const int er = (lane >> 4) * 4;
  const int ec = lane & 15;
#pragma unroll
  for (int j = 0; j < 4; j++) {
    const int col = n0 + wn + j * 16 + ec;
    const float bv = (col < nsplit) ? bias1[col] : bias2[col - nsplit];
#pragma unroll
    for (int i = 0; i < 4; i++) {
      const int rbase = m0 + wm + i * 16 + er;
#pragma unroll
      for (int r = 0; r < 4; r++) {
        const float v = acc[i][j][r] + bv;
        if constexpr (BF16OUT)
          ((unsigned short*)Cv)[(size_t)(rbase + r) * N + col] = f2bf(v);
        else
          ((float*)Cv)[(size_t)(rbase + r) * N + col] = v;
      }
    }
  }
}

// ---------------------------------------------------------------------------
// RoPE in-place on q columns of QKV bf16 (B,S,2304).
// ---------------------------------------------------------------------------
__global__ __launch_bounds__(256) void rope_q_bf16(unsigned short* __restrict__ QKV)
{
  const int row = blockIdx.x;        // b*S + s
  const int s   = row & (Ss - 1);
  const int t   = threadIdx.x;
  const int h   = t >> 4, p = t & 15;
  unsigned short* base = QKV + (size_t)row * NQKV + h * DHd + p * 4;

  union { ushort4 v; unsigned short a[4]; } lo, hi, olo, ohi;
  lo.v = *(ushort4*)base;
  hi.v = *(ushort4*)(base + 64);
#pragma unroll
  for (int d = 0; d < 4; d++) {
    const int i = p * 4 + d;
    const float invf = exp2f(-(float)i * (13.287712379549449f / 64.0f)); // 10000^(-i/64)
    const float ang = (float)s * invf;
    const float c = cosf(ang), sn = sinf(ang);
    const float l = bf2f(lo.a[d]), hh = bf2f(hi.a[d]);
    olo.a[d] = f2bf(l * c - hh * sn);
    ohi.a[d] = f2bf(hh * c + l * sn);
  }
  *(ushort4*)base        = olo.v;
  *(ushort4*)(base + 64) = ohi.v;
}

// ---------------------------------------------------------------------------
// prep_kv: from QKV bf16 (B,S,2304) — k cols [2048,2176), v cols [2176,2304) —
// produce Kb (B,S,128) roped and Vt (B,128,S) transposed.
// ---------------------------------------------------------------------------
__global__ __launch_bounds__(256) void prep_kv(
    const unsigned short* __restrict__ QKV,
    unsigned short* __restrict__ Kb,
    unsigned short* __restrict__ Vt)
{
  __shared__ unsigned short Vtile[64 * 136];   // [s_local][d], padded

  const int blk = blockIdx.x;          // b*32 + stile
  const int b   = blk >> 5;
  const int s0  = (blk & 31) * 64;
  const int t   = threadIdx.x;

  // --- rope K
  {
    const int r = t >> 2, p = t & 3;
    const int row = blk * 64 + r;
    const int s = row & (Ss - 1);
    const unsigned short* src = QKV + (size_t)row * NQKV + 2048 + p * 16;
    union { uint4 v[2]; unsigned short a[16]; } lo, hi, ol, oh;
    lo.v[0] = *(const uint4*)src;        lo.v[1] = *(const uint4*)(src + 8);
    hi.v[0] = *(const uint4*)(src + 64); hi.v[1] = *(const uint4*)(src + 72);
#pragma unroll
    for (int e = 0; e < 16; e++) {
      const int i = p * 16 + e;
      const float invf = exp2f(-(float)i * (13.287712379549449f / 64.0f));
      const float ang = (float)s * invf;
      const float c = cosf(ang), sn = sinf(ang);
      const float l = bf2f(lo.a[e]), hh = bf2f(hi.a[e]);
      ol.a[e] = f2bf(l * c - hh * sn);
      oh.a[e] = f2bf(hh * c + l * sn);
    }
    unsigned short* dst = Kb + (size_t)row * 128 + p * 16;
    *(uint4*)dst        = ol.v[0]; *(uint4*)(dst + 8)  = ol.v[1];
    *(uint4*)(dst + 64) = oh.v[0]; *(uint4*)(dst + 72) = oh.v[1];
  }

  // --- stage V into LDS, s-major
#pragma unroll
  for (int c = 0; c < 4; c++) {
    const int id = c * 256 + t;
    const int vr = id >> 4, cc = id & 15;
    *(uint4*)&Vtile[vr * 136 + cc * 8] =
        *(const uint4*)(QKV + (size_t)(blk * 64 + vr) * NQKV + 2176 + cc * 8);
  }
  __syncthreads();

  // --- write Vt rows
  {
    const int d = t >> 1, half = t & 1;
    union { uint4 v[4]; unsigned short a[32]; } val;
#pragma unroll
    for (int kk = 0; kk < 32; kk++)
      val.a[kk] = Vtile[(half * 32 + kk) * 136 + d];
    unsigned short* dst = Vt + ((size_t)(b * 128 + d)) * Ss + s0 + half * 32;
#pragma unroll
    for (int c = 0; c < 4; c++) *(uint4*)(dst + c * 8) = val.v[c];
  }
}

// ---------------------------------------------------------------------------
// flash_v7: causal MQA attention, m97-style staged MFMA, max-free softmax.
// v5 single-buffered structure + CU-load-balancing qt swizzle.
//
// Grid: flat 1024 blocks, 256 threads = 4 waves. Blocks co-resident on a CU
// are spaced 256 apart in flat index (8-XCD round-robin x 32 CU); with the
// naive decode they would all share one qt (causal work qt+1 in 1..32 ->
// CU work 4..128 tile-units, 2x makespan inflation; measured as 19.7%
// time-avg occupancy). Swizzle: flat g -> (k = g>>8, qt' = g&31, m = (g>>5)&7);
// hb = m + 8k; qt = perm_k(qt') with perm set {q, 31-q, (q+16)&31,
// 31-((q+16)&31)} -> every CU slot's 4 blocks sum to 66 tile-units. Bijective.
//
// LDS: K in 4 dh-panels [64 keys x 32 dh] (64B rows), V in 2 key-panels
// [128 dh x 32 keys] (64B rows), filled by global_load_lds width-16.
// S^T = K.Q^T; p=exp2(s*scale) (max-free); P^T C->B layout via 8 bpermutes;
// O^T = V^T.P^T.
// ---------------------------------------------------------------------------
__global__ __launch_bounds__(256, 4) void flash_v7(
    const unsigned short* __restrict__ QKV,  // (B,S,2304), q roped in [0,2048)
    const unsigned short* __restrict__ Kb,   // (B,S,128) roped
    const unsigned short* __restrict__ Vt,   // (B,128,S)
    unsigned short* __restrict__ attn)       // (B,S,2048) bf16
{
  __shared__ unsigned short Ks[4 * 64 * 32];   // panel kf: [key][dh32], 16 KB
  __shared__ unsigned short Vs[2 * 128 * 32];  // panel ks2: [dh][key32], 16 KB

  // --- load-balancing decode
  const int g   = (int)blockIdx.x;
  const int k4  = g >> 8;              // 0..3
  const int qtp = g & 31;
  const int m   = (g >> 5) & 7;
  const int hb  = m + 8 * k4;          // 0..31
  const int h   = hb & 15;
  const int b   = hb >> 4;
  const int q2  = (k4 & 2) ? ((qtp + 16) & 31) : qtp;
  const int qt  = (k4 & 1) ? (31 - q2) : q2;

  const int q0 = qt * 64;
  const int tid = threadIdx.x;
  const int w = tid >> 6, lane = tid & 63;
  const int lg = lane >> 4, lm = lane & 15;
  const int qrow = q0 + w * 16 + lm;           // this lane's q-row
  const int qrow_hi = q0 + w * 16 + 15;        // wave's last q-row

  // Q as B-operand frags: [kf]: lane: n=qrow(lm), k = kf*32 + lg*8 + j (dh)
  bf16x8 qf[4];
  {
    const unsigned short* qp =
        QKV + (size_t)(b * Ss + qrow) * NQKV + h * DHd + lg * 8;
#pragma unroll
    for (int kf = 0; kf < 4; kf++) qf[kf] = *(const bf16x8*)(qp + kf * 32);
  }

  // O^T accumulator, C-layout: element (dh = dt*16 + 4*lg + r, qrow = lm)
  f32x4 ot[8];
#pragma unroll
  for (int dt = 0; dt < 8; dt++) ot[dt] = (f32x4){0.f, 0.f, 0.f, 0.f};
  float lsum = 0.f;

  const float sscale = 0.08838834764831845f * 1.4426950408889634f; // /sqrt(128)*log2e

  // staging lane addresses
  const int sr  = lane >> 2;          // row-within-16
  const int sc8 = (lane & 3) * 8;     // 16B chunk
  const unsigned short* kg =
      Kb + (size_t)b * Ss * 128 + (size_t)sr * 128 + w * 32 + sc8;
  const unsigned short* vg =
      Vt + (size_t)b * 128 * Ss + (size_t)(w * 32 + sr) * Ss + sc8;
  unsigned short* ksl  = &Ks[w * 2048];             // panel w (dh w*32..+31)
  unsigned short* vsl0 = &Vs[(w * 32) * 32];        // ks2=0, dh rows w*32..
  unsigned short* vsl1 = &Vs[4096 + (w * 32) * 32]; // ks2=1

  // transpose shuffle sources (C->B layout, within a 32-key half)
  const int addr0 = (2 * (lg & 1)) * 16 + lm;   // dwords 0,1
  const int addr1 = addr0 + 16;                 // dwords 2,3
  const bool sel_hi = (lg & 2) != 0;

  // one 32-key half: S^T tiles tA,tA+1 -> exp -> transpose -> PV on panel VsP
  auto half32 = [&](int keybase, int tA, const unsigned short* VsP) {
    f32x4 s[2];
    s[0] = (f32x4){0.f, 0.f, 0.f, 0.f};
    s[1] = (f32x4){0.f, 0.f, 0.f, 0.f};
#pragma unroll
    for (int kf = 0; kf < 4; kf++) {
      const bf16x8 k0 = *(const bf16x8*)&Ks[kf * 2048 + ((tA)     * 16 + lm) * 32 + lg * 8];
      const bf16x8 k1 = *(const bf16x8*)&Ks[kf * 2048 + ((tA + 1) * 16 + lm) * 32 + lg * 8];
      s[0] = mfma16(k0, qf[kf], s[0]);
      s[1] = mfma16(k1, qf[kf], s[1]);
    }
    // mask + exp2 (max-free) + pack
    int pk[2][2];
#pragma unroll
    for (int t = 0; t < 2; t++) {
      float p[4];
#pragma unroll
      for (int r = 0; r < 4; r++) {
        const int key = keybase + t * 16 + 4 * lg + r;
        const float ev = exp2f(s[t][r] * sscale);
        p[r] = (key <= qrow) ? ev : 0.f;
        lsum += p[r];
      }
      pk[t][0] = pk2bf(p[0], p[1]);
      pk[t][1] = pk2bf(p[2], p[3]);
    }
    // C-layout -> B-layout transpose (8 bpermutes)
    union { int d[4]; bf16x8 v; } pb;
#pragma unroll
    for (int d = 0; d < 4; d++) {
      const int src = (d < 2) ? addr0 : addr1;
      const int v0 = __shfl(pk[0][d & 1], src);
      const int v1 = __shfl(pk[1][d & 1], src);
      pb.d[d] = sel_hi ? v1 : v0;
    }
    // O^T += V^T(32 keys) · P^T
#pragma unroll
    for (int dt = 0; dt < 8; dt++) {
      const bf16x8 vfrag = *(const bf16x8*)&VsP[(dt * 16 + lm) * 32 + lg * 8];
      ot[dt] = mfma16(vfrag, pb.v, ot[dt]);
    }
  };

  for (int j0 = 0; j0 <= q0; j0 += 64) {
    __syncthreads();            // previous iteration's LDS readers done
    // stage K panel w (dh w*32..+31, keys j0..j0+63): 4 x 1KB
#pragma unroll
    for (int i = 0; i < 4; i++)
      GLOAD16(kg + (size_t)(j0 + i * 16) * 128, ksl + i * 512);
    // stage V dh-rows w*32..+31, both key panels: 4 x 1KB
#pragma unroll
    for (int i = 0; i < 2; i++) {
      GLOAD16(vg + (size_t)(i * 16) * Ss + j0,      vsl0 + i * 512);
      GLOAD16(vg + (size_t)(i * 16) * Ss + j0 + 32, vsl1 + i * 512);
    }
    __syncthreads();            // vmcnt(0) drained before use

    half32(j0, 0, &Vs[0]);                      // keys j0..j0+31
    if (j0 + 32 <= qrow_hi)                     // wave-uniform skip
      half32(j0 + 32, 2, &Vs[4096]);            // keys j0+32..j0+63
  }

  // reduce lsum over the 4 lg groups (same lm = same qrow)
  lsum += __shfl_xor(lsum, 16);
  lsum += __shfl_xor(lsum, 32);
  const float inv = 1.0f / lsum;

  // store: lane covers (qrow, dh = dt*16 + 4lg + 0..3)
  unsigned short* dst = attn + (size_t)(b * Ss + qrow) * Dd + h * DHd + lg * 4;
#pragma unroll
  for (int dt = 0; dt < 8; dt++) {
    ushort4 o4;
    o4.x = f2bf(ot[dt][0] * inv);
    o4.y = f2bf(ot[dt][1] * inv);
    o4.z = f2bf(ot[dt][2] * inv);
    o4.w = f2bf(ot[dt][3] * inv);
    *(ushort4*)(dst + dt * 16) = o4;
  }
}

// ---------------------------------------------------------------------------
extern "C" void kernel_launch(void* const* d_in, const int* in_sizes, int n_in,
                              void* d_out, int out_size, void* d_ws, size_t ws_size,
                              hipStream_t stream) {
  const float* x   = (const float*)d_in[0];   // (B,S,D)
  const float* qw  = (const float*)d_in[1];   // (2048, 2048)
  const float* qb  = (const float*)d_in[2];
  const float* kvw = (const float*)d_in[3];   // (256, 2048)
  const float* kvb = (const float*)d_in[4];
  const float* ow  = (const float*)d_in[5];   // (2048, 2048)
  const float* ob  = (const float*)d_in[6];
  float* out = (float*)d_out;

  // workspace layout (bf16 elements):
  //   wqkv @ 0          (2304 x 2048)   qw rows 0-2047, kvw 2048-2303
  //   owb  @ 4,718,592  (2048 x 2048)
  //   xb   @ 8,912,896  (4096 x 2048)   -> reused as attn_b
  //   QKV  @ 17,301,504 (4096 x 2304)
  //   Kb   @ 26,738,688 (4096 x 128)
  //   Vt   @ 27,262,976 (2 x 128 x 2048)
  unsigned short* wsb    = (unsigned short*)d_ws;
  unsigned short* wqkv   = wsb;
  unsigned short* owb    = wsb + 4718592;
  unsigned short* xb     = wsb + 8912896;
  unsigned short* attn_b = xb;                 // alias: xb dead after QKV gemm
  unsigned short* QKV    = wsb + 17301504;
  unsigned short* Kb     = wsb + 26738688;
  unsigned short* Vt     = wsb + 27262976;

  // 1. all fp32->bf16 casts in one kernel
  cast_all<<<16896, 256, 0, stream>>>(qw, kvw, ow, x, wqkv);

  // 2. merged QKV projection: (4096 x 2304) = xb @ wqkv^T + [qb|kvb]
  gemm_bt_mfma<true><<<dim3(NQKV / TN, BS / TM), 256, 0, stream>>>(
      xb, wqkv, qb, kvb, 2048, QKV, BS, NQKV, Dd);

  // 3. RoPE q in-place; 4. K rope + V transpose
  rope_q_bf16<<<BS, 256, 0, stream>>>(QKV);
  prep_kv<<<BS / 64, 256, 0, stream>>>(QKV, Kb, Vt);

  // 5. flash attention (load-balanced qt swizzle)
  flash_v7<<<1024, 256, 0, stream>>>(QKV, Kb, Vt, attn_b);

  // 6. O projection: out = attn @ ow^T + ob (fp32 out)
  gemm_bt_mfma<false><<<dim3(Dd / TN, BS / TM), 256, 0, stream>>>(
      attn_b, owb, ob, ob, Dd, out, BS, Dd, Dd);
}

// Round 3
// 319.452 us; speedup vs baseline: 1.1731x; 1.0154x over previous
//
#include <hip/hip_runtime.h>
#include <math.h>

// Problem constants (fixed by the reference)
constexpr int Bb  = 2;
constexpr int Ss  = 2048;
constexpr int Dd  = 2048;
constexpr int Hh  = 16;
constexpr int DHd = 128;
constexpr int BS  = Bb * Ss;   // 4096
constexpr int NQKV = 2304;     // 2048 q + 128 k + 128 v

typedef __bf16 bf16x8 __attribute__((ext_vector_type(8)));
typedef float  f32x4  __attribute__((ext_vector_type(4)));

// fp32 -> bf16 (RNE), bit-level
static __device__ __forceinline__ unsigned short f2bf(float f) {
  union { float f; unsigned int u; } a; a.f = f;
  unsigned int u = a.u;
  unsigned int r = (u + 0x7fffu + ((u >> 16) & 1u)) >> 16;
  return (unsigned short)r;
}
static __device__ __forceinline__ float bf2f(unsigned short u) {
  union { unsigned int u; float f; } a; a.u = ((unsigned int)u) << 16;
  return a.f;
}
// pack two fp32 -> one dword of 2 bf16 (lo = first)
static __device__ __forceinline__ int pk2bf(float lo, float hi) {
  return (int)((unsigned int)f2bf(lo) | ((unsigned int)f2bf(hi) << 16));
}
static __device__ __forceinline__ f32x4 mfma16(bf16x8 a, bf16x8 b, f32x4 c) {
  return __builtin_amdgcn_mfma_f32_16x16x32_bf16(a, b, c, 0, 0, 0);
}

// ---------------------------------------------------------------------------
// cast ALL fp32 inputs -> bf16 into one contiguous ws region:
//   [qw (2048x2048) | kvw (256x2048) | ow (2048x2048) | x (4096x2048)]
// ---------------------------------------------------------------------------
__global__ __launch_bounds__(256) void cast_all(
    const float* __restrict__ qw, const float* __restrict__ kvw,
    const float* __restrict__ ow, const float* __restrict__ x,
    unsigned short* __restrict__ dst)
{
  const int i = blockIdx.x * 256 + threadIdx.x;   // grid sized exactly
  const float* src; int off;
  if (i < 1048576)      { src = qw;  off = 0; }
  else if (i < 1179648) { src = kvw; off = 1048576; }
  else if (i < 2228224) { src = ow;  off = 1179648; }
  else                  { src = x;   off = 2228224; }
  const float4 v = ((const float4*)src)[i - off];
  ushort4 o;
  o.x = f2bf(v.x); o.y = f2bf(v.y); o.z = f2bf(v.z); o.w = f2bf(v.w);
  ((ushort4*)dst)[i] = o;
}

// ---------------------------------------------------------------------------
// bf16 MFMA GEMM: C[M][N] = A[M][K] @ Bw[N][K]^T + bias(col).
// bias(col) = col < nsplit ? bias1[col] : bias2[col-nsplit]  (merged QKV).
// 128x128 tile, BK=32, 256 threads, global_load_lds width-16 staging.
// ---------------------------------------------------------------------------
#define TM 128
#define TN 128
#define TK 32

#define GLOAD16(gp, lp)                                                        \
  __builtin_amdgcn_global_load_lds(                                            \
      (const __attribute__((address_space(1))) void*)(gp),                     \
      (__attribute__((address_space(3))) void*)(lp), 16, 0, 0)

template <bool BF16OUT>
__global__ __launch_bounds__(256) void gemm_bt_mfma(
    const unsigned short* __restrict__ A,    // M x K bf16
    const unsigned short* __restrict__ Bw,   // N x K bf16
    const float* __restrict__ bias1,
    const float* __restrict__ bias2,
    int nsplit,
    void* __restrict__ Cv,                   // M x N (fp32 or bf16)
    int M, int N, int K)
{
  __shared__ unsigned short As[TM * TK];   // 8 KB
  __shared__ unsigned short Bs[TN * TK];   // 8 KB

  const int tid  = threadIdx.x;
  const int w    = tid >> 6;
  const int lane = tid & 63;
  const int m0   = blockIdx.y * TM;
  const int n0   = blockIdx.x * TN;
  const int wm   = (w >> 1) * 64;
  const int wn   = (w & 1) * 64;

  f32x4 acc[4][4];
#pragma unroll
  for (int i = 0; i < 4; i++)
#pragma unroll
    for (int j = 0; j < 4; j++) acc[i][j] = (f32x4){0.f, 0.f, 0.f, 0.f};

  const int srow = lane >> 2;
  const int scol = (lane & 3) * 8;
  const unsigned short* aG0 = A  + (size_t)(m0 +      w * 16 + srow) * K + scol;
  const unsigned short* aG1 = A  + (size_t)(m0 + 64 + w * 16 + srow) * K + scol;
  const unsigned short* bG0 = Bw + (size_t)(n0 +      w * 16 + srow) * K + scol;
  const unsigned short* bG1 = Bw + (size_t)(n0 + 64 + w * 16 + srow) * K + scol;
  unsigned short* aL0 = &As[(     w * 16) * TK];
  unsigned short* aL1 = &As[(64 + w * 16) * TK];
  unsigned short* bL0 = &Bs[(     w * 16) * TK];
  unsigned short* bL1 = &Bs[(64 + w * 16) * TK];

  const int fr = lane & 15;
  const int fk = (lane >> 4) * 8;

  for (int k0 = 0; k0 < K; k0 += TK) {
    __syncthreads();
    GLOAD16(aG0 + k0, aL0);
    GLOAD16(aG1 + k0, aL1);
    GLOAD16(bG0 + k0, bL0);
    GLOAD16(bG1 + k0, bL1);
    __syncthreads();

    bf16x8 af[4], bfr[4];
#pragma unroll
    for (int i = 0; i < 4; i++)
      af[i] = *(const bf16x8*)&As[(wm + i * 16 + fr) * TK + fk];
#pragma unroll
    for (int j = 0; j < 4; j++)
      bfr[j] = *(const bf16x8*)&Bs[(wn + j * 16 + fr) * TK + fk];
#pragma unroll
    for (int i = 0; i < 4; i++)
#pragma unroll
      for (int j = 0; j < 4; j++)
        acc[i][j] = mfma16(af[i], bfr[j], acc[i][j]);
  }

  const int er = (lane >> 4) * 4;
  const int ec = lane & 15;
#pragma unroll
  for (int j = 0; j < 4; j++) {
    const int col = n0 + wn + j * 16 + ec;
    const float bv = (col < nsplit) ? bias1[col] : bias2[col - nsplit];
#pragma unroll
    for (int i = 0; i < 4; i++) {
      const int rbase = m0 + wm + i * 16 + er;
#pragma unroll
      for (int r = 0; r < 4; r++) {
        const float v = acc[i][j][r] + bv;
        if constexpr (BF16OUT)
          ((unsigned short*)Cv)[(size_t)(rbase + r) * N + col] = f2bf(v);
        else
          ((float*)Cv)[(size_t)(rbase + r) * N + col] = v;
      }
    }
  }
}

// ---------------------------------------------------------------------------
// prep_kv: from QKV bf16 (B,S,2304) — k cols [2048,2176), v cols [2176,2304) —
// produce Kb (B,S,128) roped and Vt (B,128,S) transposed.
// ---------------------------------------------------------------------------
__global__ __launch_bounds__(256) void prep_kv(
    const unsigned short* __restrict__ QKV,
    unsigned short* __restrict__ Kb,
    unsigned short* __restrict__ Vt)
{
  __shared__ unsigned short Vtile[64 * 136];   // [s_local][d], padded

  const int blk = blockIdx.x;          // b*32 + stile
  const int b   = blk >> 5;
  const int s0  = (blk & 31) * 64;
  const int t   = threadIdx.x;

  // --- rope K
  {
    const int r = t >> 2, p = t & 3;
    const int row = blk * 64 + r;
    const int s = row & (Ss - 1);
    const unsigned short* src = QKV + (size_t)row * NQKV + 2048 + p * 16;
    union { uint4 v[2]; unsigned short a[16]; } lo, hi, ol, oh;
    lo.v[0] = *(const uint4*)src;        lo.v[1] = *(const uint4*)(src + 8);
    hi.v[0] = *(const uint4*)(src + 64); hi.v[1] = *(const uint4*)(src + 72);
#pragma unroll
    for (int e = 0; e < 16; e++) {
      const int i = p * 16 + e;
      const float invf = exp2f(-(float)i * (13.287712379549449f / 64.0f));
      const float ang = (float)s * invf;
      const float c = cosf(ang), sn = sinf(ang);
      const float l = bf2f(lo.a[e]), hh = bf2f(hi.a[e]);
      ol.a[e] = f2bf(l * c - hh * sn);
      oh.a[e] = f2bf(hh * c + l * sn);
    }
    unsigned short* dst = Kb + (size_t)row * 128 + p * 16;
    *(uint4*)dst        = ol.v[0]; *(uint4*)(dst + 8)  = ol.v[1];
    *(uint4*)(dst + 64) = oh.v[0]; *(uint4*)(dst + 72) = oh.v[1];
  }

  // --- stage V into LDS, s-major
#pragma unroll
  for (int c = 0; c < 4; c++) {
    const int id = c * 256 + t;
    const int vr = id >> 4, cc = id & 15;
    *(uint4*)&Vtile[vr * 136 + cc * 8] =
        *(const uint4*)(QKV + (size_t)(blk * 64 + vr) * NQKV + 2176 + cc * 8);
  }
  __syncthreads();

  // --- write Vt rows
  {
    const int d = t >> 1, half = t & 1;
    union { uint4 v[4]; unsigned short a[32]; } val;
#pragma unroll
    for (int kk = 0; kk < 32; kk++)
      val.a[kk] = Vtile[(half * 32 + kk) * 136 + d];
    unsigned short* dst = Vt + ((size_t)(b * 128 + d)) * Ss + s0 + half * 32;
#pragma unroll
    for (int c = 0; c < 4; c++) *(uint4*)(dst + c * 8) = val.v[c];
  }
}

// ---------------------------------------------------------------------------
// flash_v8: causal MQA attention. v7 (qt load-balance swizzle) plus:
//  (a) conflict-free LDS: frag reads had 4-way bank conflicts (16B chunks at
//      64B row stride -> bank-groups {lg,4+lg} only). Fix: slot-XOR swizzle
//      slot' = slot ^ ((row>>1)&3), applied on the WRITE side by permuting the
//      per-lane GLOBAL source chunk (LDS dest stays linear, rule: gload_lds
//      can't scatter) and on the READ side via lane-constant klg.
//  (b) RoPE(Q) fused in-register (qf[kf] pairs with qf[kf+2] elementwise) —
//      the standalone rope_q pass and its 33.6 MB round-trip are deleted.
// ---------------------------------------------------------------------------
__global__ __launch_bounds__(256, 4) void flash_v8(
    const unsigned short* __restrict__ QKV,  // (B,S,2304), q RAW (rope here)
    const unsigned short* __restrict__ Kb,   // (B,S,128) roped
    const unsigned short* __restrict__ Vt,   // (B,128,S)
    unsigned short* __restrict__ attn)       // (B,S,2048) bf16
{
  __shared__ unsigned short Ks[4 * 64 * 32];   // panel kf: [key][dh32], 16 KB
  __shared__ unsigned short Vs[2 * 128 * 32];  // panel ks2: [dh][key32], 16 KB

  // --- load-balancing decode (CU slot sums of qt+1 are all 66)
  const int g   = (int)blockIdx.x;
  const int k4  = g >> 8;              // 0..3
  const int qtp = g & 31;
  const int m   = (g >> 5) & 7;
  const int hb  = m + 8 * k4;          // 0..31
  const int h   = hb & 15;
  const int b   = hb >> 4;
  const int q2  = (k4 & 2) ? ((qtp + 16) & 31) : qtp;
  const int qt  = (k4 & 1) ? (31 - q2) : q2;

  const int q0 = qt * 64;
  const int tid = threadIdx.x;
  const int w = tid >> 6, lane = tid & 63;
  const int lg = lane >> 4, lm = lane & 15;
  const int qrow = q0 + w * 16 + lm;           // this lane's q-row (= seq pos)
  const int qrow_hi = q0 + w * 16 + 15;        // wave's last q-row

  // swizzled frag slot: row contributions >=16 vanish mod 4 -> lane-constant
  const int klg = lg ^ ((lm >> 1) & 3);

  // Q as B-operand frags with fused RoPE: qf[kf][j] = q[dh=kf*32+lg*8+j];
  // pair (i, i+64) lives at (qf[kf], qf[kf+2]) same j. Identical math to the
  // old rope_q kernel (f32 compute, cosf/sinf, f2bf round).
  bf16x8 qf[4];
  {
    const unsigned short* qp =
        QKV + (size_t)(b * Ss + qrow) * NQKV + h * DHd + lg * 8;
    union U8 { bf16x8 v; unsigned short a[8]; };
    U8 lo0, lo1, hi0, hi1, ol0, ol1, oh0, oh1;
    lo0.v = *(const bf16x8*)(qp);
    lo1.v = *(const bf16x8*)(qp + 32);
    hi0.v = *(const bf16x8*)(qp + 64);
    hi1.v = *(const bf16x8*)(qp + 96);
    const float fs = (float)qrow;
#pragma unroll
    for (int j = 0; j < 8; j++) {
      {
        const int i = lg * 8 + j;                       // 0..31
        const float invf = exp2f(-(float)i * (13.287712379549449f / 64.0f));
        const float ang = fs * invf;
        const float c = cosf(ang), sn = sinf(ang);
        const float l = bf2f(lo0.a[j]), hh = bf2f(hi0.a[j]);
        ol0.a[j] = f2bf(l * c - hh * sn);
        oh0.a[j] = f2bf(hh * c + l * sn);
      }
      {
        const int i = 32 + lg * 8 + j;                  // 32..63
        const float invf = exp2f(-(float)i * (13.287712379549449f / 64.0f));
        const float ang = fs * invf;
        const float c = cosf(ang), sn = sinf(ang);
        const float l = bf2f(lo1.a[j]), hh = bf2f(hi1.a[j]);
        ol1.a[j] = f2bf(l * c - hh * sn);
        oh1.a[j] = f2bf(hh * c + l * sn);
      }
    }
    qf[0] = ol0.v; qf[1] = ol1.v; qf[2] = oh0.v; qf[3] = oh1.v;
  }

  // O^T accumulator, C-layout: element (dh = dt*16 + 4*lg + r, qrow = lm)
  f32x4 ot[8];
#pragma unroll
  for (int dt = 0; dt < 8; dt++) ot[dt] = (f32x4){0.f, 0.f, 0.f, 0.f};
  float lsum = 0.f;

  const float sscale = 0.08838834764831845f * 1.4426950408889634f; // /sqrt(128)*log2e

  // staging lane addresses; global chunk permuted so linear LDS dest holds
  // the slot-swizzled layout: chunk(lane) = (lane&3) ^ ((lane>>3)&3)
  const int sr  = lane >> 2;                           // row-within-16
  const int sc8 = ((lane & 3) ^ ((lane >> 3) & 3)) * 8;  // swizzled 16B chunk
  const unsigned short* kg =
      Kb + (size_t)b * Ss * 128 + (size_t)sr * 128 + w * 32 + sc8;
  const unsigned short* vg =
      Vt + (size_t)b * 128 * Ss + (size_t)(w * 32 + sr) * Ss + sc8;
  unsigned short* ksl  = &Ks[w * 2048];             // panel w (dh w*32..+31)
  unsigned short* vsl0 = &Vs[(w * 32) * 32];        // ks2=0, dh rows w*32..
  unsigned short* vsl1 = &Vs[4096 + (w * 32) * 32]; // ks2=1

  // transpose shuffle sources (C->B layout, within a 32-key half)
  const int addr0 = (2 * (lg & 1)) * 16 + lm;   // dwords 0,1
  const int addr1 = addr0 + 16;                 // dwords 2,3
  const bool sel_hi = (lg & 2) != 0;

  // one 32-key half: S^T tiles tA,tA+1 -> exp -> transpose -> PV on panel VsP
  auto half32 = [&](int keybase, int tA, const unsigned short* VsP) {
    f32x4 s[2];
    s[0] = (f32x4){0.f, 0.f, 0.f, 0.f};
    s[1] = (f32x4){0.f, 0.f, 0.f, 0.f};
#pragma unroll
    for (int kf = 0; kf < 4; kf++) {
      const bf16x8 k0 = *(const bf16x8*)&Ks[kf * 2048 + ((tA)     * 16 + lm) * 32 + klg * 8];
      const bf16x8 k1 = *(const bf16x8*)&Ks[kf * 2048 + ((tA + 1) * 16 + lm) * 32 + klg * 8];
      s[0] = mfma16(k0, qf[kf], s[0]);
      s[1] = mfma16(k1, qf[kf], s[1]);
    }
    // mask + exp2 (max-free) + pack
    int pk[2][2];
#pragma unroll
    for (int t = 0; t < 2; t++) {
      float p[4];
#pragma unroll
      for (int r = 0; r < 4; r++) {
        const int key = keybase + t * 16 + 4 * lg + r;
        const float ev = exp2f(s[t][r] * sscale);
        p[r] = (key <= qrow) ? ev : 0.f;
        lsum += p[r];
      }
      pk[t][0] = pk2bf(p[0], p[1]);
      pk[t][1] = pk2bf(p[2], p[3]);
    }
    // C-layout -> B-layout transpose (8 bpermutes)
    union { int d[4]; bf16x8 v; } pb;
#pragma unroll
    for (int d = 0; d < 4; d++) {
      const int src = (d < 2) ? addr0 : addr1;
      const int v0 = __shfl(pk[0][d & 1], src);
      const int v1 = __shfl(pk[1][d & 1], src);
      pb.d[d] = sel_hi ? v1 : v0;
    }
    // O^T += V^T(32 keys) · P^T
#pragma unroll
    for (int dt = 0; dt < 8; dt++) {
      const bf16x8 vfrag = *(const bf16x8*)&VsP[(dt * 16 + lm) * 32 + klg * 8];
      ot[dt] = mfma16(vfrag, pb.v, ot[dt]);
    }
  };

  for (int j0 = 0; j0 <= q0; j0 += 64) {
    __syncthreads();            // previous iteration's LDS readers done
    // stage K panel w (dh w*32..+31, keys j0..j0+63): 4 x 1KB
#pragma unroll
    for (int i = 0; i < 4; i++)
      GLOAD16(kg + (size_t)(j0 + i * 16) * 128, ksl + i * 512);
    // stage V dh-rows w*32..+31, both key panels: 4 x 1KB
#pragma unroll
    for (int i = 0; i < 2; i++) {
      GLOAD16(vg + (size_t)(i * 16) * Ss + j0,      vsl0 + i * 512);
      GLOAD16(vg + (size_t)(i * 16) * Ss + j0 + 32, vsl1 + i * 512);
    }
    __syncthreads();            // vmcnt(0) drained before use

    half32(j0, 0, &Vs[0]);                      // keys j0..j0+31
    if (j0 + 32 <= qrow_hi)                     // wave-uniform skip
      half32(j0 + 32, 2, &Vs[4096]);            // keys j0+32..j0+63
  }

  // reduce lsum over the 4 lg groups (same lm = same qrow)
  lsum += __shfl_xor(lsum, 16);
  lsum += __shfl_xor(lsum, 32);
  const float inv = 1.0f / lsum;

  // store: lane covers (qrow, dh = dt*16 + 4lg + 0..3)
  unsigned short* dst = attn + (size_t)(b * Ss + qrow) * Dd + h * DHd + lg * 4;
#pragma unroll
  for (int dt = 0; dt < 8; dt++) {
    ushort4 o4;
    o4.x = f2bf(ot[dt][0] * inv);
    o4.y = f2bf(ot[dt][1] * inv);
    o4.z = f2bf(ot[dt][2] * inv);
    o4.w = f2bf(ot[dt][3] * inv);
    *(ushort4*)(dst + dt * 16) = o4;
  }
}

// ---------------------------------------------------------------------------
extern "C" void kernel_launch(void* const* d_in, const int* in_sizes, int n_in,
                              void* d_out, int out_size, void* d_ws, size_t ws_size,
                              hipStream_t stream) {
  const float* x   = (const float*)d_in[0];   // (B,S,D)
  const float* qw  = (const float*)d_in[1];   // (2048, 2048)
  const float* qb  = (const float*)d_in[2];
  const float* kvw = (const float*)d_in[3];   // (256, 2048)
  const float* kvb = (const float*)d_in[4];
  const float* ow  = (const float*)d_in[5];   // (2048, 2048)
  const float* ob  = (const float*)d_in[6];
  float* out = (float*)d_out;

  // workspace layout (bf16 elements):
  //   wqkv @ 0          (2304 x 2048)   qw rows 0-2047, kvw 2048-2303
  //   owb  @ 4,718,592  (2048 x 2048)
  //   xb   @ 8,912,896  (4096 x 2048)   -> reused as attn_b
  //   QKV  @ 17,301,504 (4096 x 2304)
  //   Kb   @ 26,738,688 (4096 x 128)
  //   Vt   @ 27,262,976 (2 x 128 x 2048)
  unsigned short* wsb    = (unsigned short*)d_ws;
  unsigned short* wqkv   = wsb;
  unsigned short* owb    = wsb + 4718592;
  unsigned short* xb     = wsb + 8912896;
  unsigned short* attn_b = xb;                 // alias: xb dead after QKV gemm
  unsigned short* QKV    = wsb + 17301504;
  unsigned short* Kb     = wsb + 26738688;
  unsigned short* Vt     = wsb + 27262976;

  // 1. all fp32->bf16 casts in one kernel
  cast_all<<<16896, 256, 0, stream>>>(qw, kvw, ow, x, wqkv);

  // 2. merged QKV projection: (4096 x 2304) = xb @ wqkv^T + [qb|kvb]
  gemm_bt_mfma<true><<<dim3(NQKV / TN, BS / TM), 256, 0, stream>>>(
      xb, wqkv, qb, kvb, 2048, QKV, BS, NQKV, Dd);

  // 3. K rope + V transpose (Q rope is fused into flash_v8)
  prep_kv<<<BS / 64, 256, 0, stream>>>(QKV, Kb, Vt);

  // 4. flash attention (balanced swizzle + conflict-free LDS + fused Q-rope)
  flash_v8<<<1024, 256, 0, stream>>>(QKV, Kb, Vt, attn_b);

  // 5. O projection: out = attn @ ow^T + ob (fp32 out)
  gemm_bt_mfma<false><<<dim3(Dd / TN, BS / TM), 256, 0, stream>>>(
      attn_b, owb, ob, ob, Dd, out, BS, Dd, Dd);
}

// Round 4
// 317.749 us; speedup vs baseline: 1.1794x; 1.0054x over previous
//
#include <hip/hip_runtime.h>
#include <math.h>

// Problem constants (fixed by the reference)
constexpr int Bb  = 2;
constexpr int Ss  = 2048;
constexpr int Dd  = 2048;
constexpr int Hh  = 16;
constexpr int DHd = 128;
constexpr int BS  = Bb * Ss;   // 4096
constexpr int NQKV = 2304;     // 2048 q + 128 k + 128 v

typedef __bf16 bf16x8 __attribute__((ext_vector_type(8)));
typedef float  f32x4  __attribute__((ext_vector_type(4)));

// fp32 -> bf16 (RNE), bit-level
static __device__ __forceinline__ unsigned short f2bf(float f) {
  union { float f; unsigned int u; } a; a.f = f;
  unsigned int u = a.u;
  unsigned int r = (u + 0x7fffu + ((u >> 16) & 1u)) >> 16;
  return (unsigned short)r;
}
static __device__ __forceinline__ float bf2f(unsigned short u) {
  union { unsigned int u; float f; } a; a.u = ((unsigned int)u) << 16;
  return a.f;
}
// pack two fp32 -> one dword of 2 bf16 (lo = first)
static __device__ __forceinline__ int pk2bf(float lo, float hi) {
  return (int)((unsigned int)f2bf(lo) | ((unsigned int)f2bf(hi) << 16));
}
static __device__ __forceinline__ f32x4 mfma16(bf16x8 a, bf16x8 b, f32x4 c) {
  return __builtin_amdgcn_mfma_f32_16x16x32_bf16(a, b, c, 0, 0, 0);
}

// ---------------------------------------------------------------------------
// cast_all: blocks [0,16896): fp32 inputs -> bf16 into one contiguous region
//   [qw (2048x2048) | kvw (256x2048) | ow (2048x2048) | x (4096x2048)]
// blocks [16896,17408): fill RoPE cos/sin table ctab[s][i], s<2048, i<64.
// ---------------------------------------------------------------------------
__global__ __launch_bounds__(256) void cast_all(
    const float* __restrict__ qw, const float* __restrict__ kvw,
    const float* __restrict__ ow, const float* __restrict__ x,
    unsigned short* __restrict__ dst,
    float2* __restrict__ ctab)
{
  const int blk = blockIdx.x;
  if (blk >= 16896) {                              // RoPE table fill
    const int id = (blk - 16896) * 256 + threadIdx.x;  // 0..131071
    const int s = id >> 6, i = id & 63;
    const float invf = exp2f(-(float)i * (13.287712379549449f / 64.0f));
    const float ang = (float)s * invf;
    ctab[id] = make_float2(cosf(ang), sinf(ang));
    return;
  }
  const int i = blk * 256 + threadIdx.x;
  const float* src; int off;
  if (i < 1048576)      { src = qw;  off = 0; }
  else if (i < 1179648) { src = kvw; off = 1048576; }
  else if (i < 2228224) { src = ow;  off = 1179648; }
  else                  { src = x;   off = 2228224; }
  const float4 v = ((const float4*)src)[i - off];
  ushort4 o;
  o.x = f2bf(v.x); o.y = f2bf(v.y); o.z = f2bf(v.z); o.w = f2bf(v.w);
  ((ushort4*)dst)[i] = o;
}

// ---------------------------------------------------------------------------
// bf16 MFMA GEMM: C[M][N] = A[M][K] @ Bw[N][K]^T + bias(col).
// bias(col) = col < nsplit ? bias1[col] : bias2[col-nsplit]  (merged QKV).
// 128x128 tile, BK=32, 256 threads, global_load_lds width-16 staging.
// ---------------------------------------------------------------------------
#define TM 128
#define TN 128
#define TK 32

#define GLOAD16(gp, lp)                                                        \
  __builtin_amdgcn_global_load_lds(                                            \
      (const __attribute__((address_space(1))) void*)(gp),                     \
      (__attribute__((address_space(3))) void*)(lp), 16, 0, 0)

template <bool BF16OUT>
__global__ __launch_bounds__(256) void gemm_bt_mfma(
    const unsigned short* __restrict__ A,    // M x K bf16
    const unsigned short* __restrict__ Bw,   // N x K bf16
    const float* __restrict__ bias1,
    const float* __restrict__ bias2,
    int nsplit,
    void* __restrict__ Cv,                   // M x N (fp32 or bf16)
    int M, int N, int K)
{
  __shared__ unsigned short As[TM * TK];   // 8 KB
  __shared__ unsigned short Bs[TN * TK];   // 8 KB

  const int tid  = threadIdx.x;
  const int w    = tid >> 6;
  const int lane = tid & 63;
  const int m0   = blockIdx.y * TM;
  const int n0   = blockIdx.x * TN;
  const int wm   = (w >> 1) * 64;
  const int wn   = (w & 1) * 64;

  f32x4 acc[4][4];
#pragma unroll
  for (int i = 0; i < 4; i++)
#pragma unroll
    for (int j = 0; j < 4; j++) acc[i][j] = (f32x4){0.f, 0.f, 0.f, 0.f};

  const int srow = lane >> 2;
  const int scol = (lane & 3) * 8;
  const unsigned short* aG0 = A  + (size_t)(m0 +      w * 16 + srow) * K + scol;
  const unsigned short* aG1 = A  + (size_t)(m0 + 64 + w * 16 + srow) * K + scol;
  const unsigned short* bG0 = Bw + (size_t)(n0 +      w * 16 + srow) * K + scol;
  const unsigned short* bG1 = Bw + (size_t)(n0 + 64 + w * 16 + srow) * K + scol;
  unsigned short* aL0 = &As[(     w * 16) * TK];
  unsigned short* aL1 = &As[(64 + w * 16) * TK];
  unsigned short* bL0 = &Bs[(     w * 16) * TK];
  unsigned short* bL1 = &Bs[(64 + w * 16) * TK];

  const int fr = lane & 15;
  const int fk = (lane >> 4) * 8;

  for (int k0 = 0; k0 < K; k0 += TK) {
    __syncthreads();
    GLOAD16(aG0 + k0, aL0);
    GLOAD16(aG1 + k0, aL1);
    GLOAD16(bG0 + k0, bL0);
    GLOAD16(bG1 + k0, bL1);
    __syncthreads();

    bf16x8 af[4], bfr[4];
#pragma unroll
    for (int i = 0; i < 4; i++)
      af[i] = *(const bf16x8*)&As[(wm + i * 16 + fr) * TK + fk];
#pragma unroll
    for (int j = 0; j < 4; j++)
      bfr[j] = *(const bf16x8*)&Bs[(wn + j * 16 + fr) * TK + fk];
#pragma unroll
    for (int i = 0; i < 4; i++)
#pragma unroll
      for (int j = 0; j < 4; j++)
        acc[i][j] = mfma16(af[i], bfr[j], acc[i][j]);
  }

  const int er = (lane >> 4) * 4;
  const int ec = lane & 15;
#pragma unroll
  for (int j = 0; j < 4; j++) {
    const int col = n0 + wn + j * 16 + ec;
    const float bv = (col < nsplit) ? bias1[col] : bias2[col - nsplit];
#pragma unroll
    for (int i = 0; i < 4; i++) {
      const int rbase = m0 + wm + i * 16 + er;
#pragma unroll
      for (int r = 0; r < 4; r++) {
        const float v = acc[i][j][r] + bv;
        if constexpr (BF16OUT)
          ((unsigned short*)Cv)[(size_t)(rbase + r) * N + col] = f2bf(v);
        else
          ((float*)Cv)[(size_t)(rbase + r) * N + col] = v;
      }
    }
  }
}

// ---------------------------------------------------------------------------
// prep_kv: from QKV bf16 (B,S,2304) — k cols [2048,2176), v cols [2176,2304) —
// produce Kb (B,S,128) roped (table-driven) and Vt (B,128,S) transposed.
// ---------------------------------------------------------------------------
__global__ __launch_bounds__(256) void prep_kv(
    const unsigned short* __restrict__ QKV,
    const float2* __restrict__ ctab,
    unsigned short* __restrict__ Kb,
    unsigned short* __restrict__ Vt)
{
  __shared__ unsigned short Vtile[64 * 136];   // [s_local][d], padded

  const int blk = blockIdx.x;          // b*32 + stile
  const int b   = blk >> 5;
  const int s0  = (blk & 31) * 64;
  const int t   = threadIdx.x;

  // --- rope K (cos/sin from table)
  {
    const int r = t >> 2, p = t & 3;
    const int row = blk * 64 + r;
    const int s = row & (Ss - 1);
    const unsigned short* src = QKV + (size_t)row * NQKV + 2048 + p * 16;
    const float2* ct = ctab + s * 64 + p * 16;
    union { uint4 v[2]; unsigned short a[16]; } lo, hi, ol, oh;
    lo.v[0] = *(const uint4*)src;        lo.v[1] = *(const uint4*)(src + 8);
    hi.v[0] = *(const uint4*)(src + 64); hi.v[1] = *(const uint4*)(src + 72);
#pragma unroll
    for (int e = 0; e < 16; e++) {
      const float2 cs = ct[e];
      const float l = bf2f(lo.a[e]), hh = bf2f(hi.a[e]);
      ol.a[e] = f2bf(l * cs.x - hh * cs.y);
      oh.a[e] = f2bf(hh * cs.x + l * cs.y);
    }
    unsigned short* dst = Kb + (size_t)row * 128 + p * 16;
    *(uint4*)dst        = ol.v[0]; *(uint4*)(dst + 8)  = ol.v[1];
    *(uint4*)(dst + 64) = oh.v[0]; *(uint4*)(dst + 72) = oh.v[1];
  }

  // --- stage V into LDS, s-major
#pragma unroll
  for (int c = 0; c < 4; c++) {
    const int id = c * 256 + t;
    const int vr = id >> 4, cc = id & 15;
    *(uint4*)&Vtile[vr * 136 + cc * 8] =
        *(const uint4*)(QKV + (size_t)(blk * 64 + vr) * NQKV + 2176 + cc * 8);
  }
  __syncthreads();

  // --- write Vt rows
  {
    const int d = t >> 1, half = t & 1;
    union { uint4 v[4]; unsigned short a[32]; } val;
#pragma unroll
    for (int kk = 0; kk < 32; kk++)
      val.a[kk] = Vtile[(half * 32 + kk) * 136 + d];
    unsigned short* dst = Vt + ((size_t)(b * 128 + d)) * Ss + s0 + half * 32;
#pragma unroll
    for (int c = 0; c < 4; c++) *(uint4*)(dst + c * 8) = val.v[c];
  }
}

// ---------------------------------------------------------------------------
// flash_v9: causal MQA attention. v8 structure (qt load-balance swizzle +
// conflict-free slot-XOR LDS + fused Q-rope) with the Q-rope trig replaced by
// cos/sin TABLE loads (ctab, 1 MB, L2-resident) — removes the 64-transcendental
// per-lane prologue that regressed v8.
// ---------------------------------------------------------------------------
__global__ __launch_bounds__(256, 4) void flash_v9(
    const unsigned short* __restrict__ QKV,  // (B,S,2304), q RAW (rope here)
    const unsigned short* __restrict__ Kb,   // (B,S,128) roped
    const unsigned short* __restrict__ Vt,   // (B,128,S)
    const float2* __restrict__ ctab,         // (2048, 64) cos/sin
    unsigned short* __restrict__ attn)       // (B,S,2048) bf16
{
  __shared__ unsigned short Ks[4 * 64 * 32];   // panel kf: [key][dh32], 16 KB
  __shared__ unsigned short Vs[2 * 128 * 32];  // panel ks2: [dh][key32], 16 KB

  // --- load-balancing decode (CU slot sums of qt+1 are all 66)
  const int g   = (int)blockIdx.x;
  const int k4  = g >> 8;              // 0..3
  const int qtp = g & 31;
  const int m   = (g >> 5) & 7;
  const int hb  = m + 8 * k4;          // 0..31
  const int h   = hb & 15;
  const int b   = hb >> 4;
  const int q2  = (k4 & 2) ? ((qtp + 16) & 31) : qtp;
  const int qt  = (k4 & 1) ? (31 - q2) : q2;

  const int q0 = qt * 64;
  const int tid = threadIdx.x;
  const int w = tid >> 6, lane = tid & 63;
  const int lg = lane >> 4, lm = lane & 15;
  const int qrow = q0 + w * 16 + lm;           // this lane's q-row (= seq pos)
  const int qrow_hi = q0 + w * 16 + 15;        // wave's last q-row

  // swizzled frag slot: row contributions >=16 vanish mod 4 -> lane-constant
  const int klg = lg ^ ((lm >> 1) & 3);

  // Q as B-operand frags with fused RoPE (table-driven):
  // qf[kf][j] = q[dh=kf*32+lg*8+j]; pair (i, i+64) is (qf[kf], qf[kf+2]).
  bf16x8 qf[4];
  {
    const unsigned short* qp =
        QKV + (size_t)(b * Ss + qrow) * NQKV + h * DHd + lg * 8;
    const float2* ct = ctab + qrow * 64 + lg * 8;
    union U8 { bf16x8 v; unsigned short a[8]; };
    U8 lo0, lo1, hi0, hi1, ol0, ol1, oh0, oh1;
    lo0.v = *(const bf16x8*)(qp);
    lo1.v = *(const bf16x8*)(qp + 32);
    hi0.v = *(const bf16x8*)(qp + 64);
    hi1.v = *(const bf16x8*)(qp + 96);
#pragma unroll
    for (int j = 0; j < 8; j++) {
      {
        const float2 cs = ct[j];                        // i = lg*8+j
        const float l = bf2f(lo0.a[j]), hh = bf2f(hi0.a[j]);
        ol0.a[j] = f2bf(l * cs.x - hh * cs.y);
        oh0.a[j] = f2bf(hh * cs.x + l * cs.y);
      }
      {
        const float2 cs = ct[32 + j];                   // i = 32+lg*8+j
        const float l = bf2f(lo1.a[j]), hh = bf2f(hi1.a[j]);
        ol1.a[j] = f2bf(l * cs.x - hh * cs.y);
        oh1.a[j] = f2bf(hh * cs.x + l * cs.y);
      }
    }
    qf[0] = ol0.v; qf[1] = ol1.v; qf[2] = oh0.v; qf[3] = oh1.v;
  }

  // O^T accumulator, C-layout: element (dh = dt*16 + 4*lg + r, qrow = lm)
  f32x4 ot[8];
#pragma unroll
  for (int dt = 0; dt < 8; dt++) ot[dt] = (f32x4){0.f, 0.f, 0.f, 0.f};
  float lsum = 0.f;

  const float sscale = 0.08838834764831845f * 1.4426950408889634f; // /sqrt(128)*log2e

  // staging lane addresses; global chunk permuted so linear LDS dest holds
  // the slot-swizzled layout: chunk(lane) = (lane&3) ^ ((lane>>3)&3)
  const int sr  = lane >> 2;                           // row-within-16
  const int sc8 = ((lane & 3) ^ ((lane >> 3) & 3)) * 8;  // swizzled 16B chunk
  const unsigned short* kg =
      Kb + (size_t)b * Ss * 128 + (size_t)sr * 128 + w * 32 + sc8;
  const unsigned short* vg =
      Vt + (size_t)b * 128 * Ss + (size_t)(w * 32 + sr) * Ss + sc8;
  unsigned short* ksl  = &Ks[w * 2048];             // panel w (dh w*32..+31)
  unsigned short* vsl0 = &Vs[(w * 32) * 32];        // ks2=0, dh rows w*32..
  unsigned short* vsl1 = &Vs[4096 + (w * 32) * 32]; // ks2=1

  // transpose shuffle sources (C->B layout, within a 32-key half)
  const int addr0 = (2 * (lg & 1)) * 16 + lm;   // dwords 0,1
  const int addr1 = addr0 + 16;                 // dwords 2,3
  const bool sel_hi = (lg & 2) != 0;

  // one 32-key half: S^T tiles tA,tA+1 -> exp -> transpose -> PV on panel VsP
  auto half32 = [&](int keybase, int tA, const unsigned short* VsP) {
    f32x4 s[2];
    s[0] = (f32x4){0.f, 0.f, 0.f, 0.f};
    s[1] = (f32x4){0.f, 0.f, 0.f, 0.f};
#pragma unroll
    for (int kf = 0; kf < 4; kf++) {
      const bf16x8 k0 = *(const bf16x8*)&Ks[kf * 2048 + ((tA)     * 16 + lm) * 32 + klg * 8];
      const bf16x8 k1 = *(const bf16x8*)&Ks[kf * 2048 + ((tA + 1) * 16 + lm) * 32 + klg * 8];
      s[0] = mfma16(k0, qf[kf], s[0]);
      s[1] = mfma16(k1, qf[kf], s[1]);
    }
    // mask + exp2 (max-free) + pack
    int pk[2][2];
#pragma unroll
    for (int t = 0; t < 2; t++) {
      float p[4];
#pragma unroll
      for (int r = 0; r < 4; r++) {
        const int key = keybase + t * 16 + 4 * lg + r;
        const float ev = exp2f(s[t][r] * sscale);
        p[r] = (key <= qrow) ? ev : 0.f;
        lsum += p[r];
      }
      pk[t][0] = pk2bf(p[0], p[1]);
      pk[t][1] = pk2bf(p[2], p[3]);
    }
    // C-layout -> B-layout transpose (8 bpermutes)
    union { int d[4]; bf16x8 v; } pb;
#pragma unroll
    for (int d = 0; d < 4; d++) {
      const int src = (d < 2) ? addr0 : addr1;
      const int v0 = __shfl(pk[0][d & 1], src);
      const int v1 = __shfl(pk[1][d & 1], src);
      pb.d[d] = sel_hi ? v1 : v0;
    }
    // O^T += V^T(32 keys) · P^T
#pragma unroll
    for (int dt = 0; dt < 8; dt++) {
      const bf16x8 vfrag = *(const bf16x8*)&VsP[(dt * 16 + lm) * 32 + klg * 8];
      ot[dt] = mfma16(vfrag, pb.v, ot[dt]);
    }
  };

  for (int j0 = 0; j0 <= q0; j0 += 64) {
    __syncthreads();            // previous iteration's LDS readers done
    // stage K panel w (dh w*32..+31, keys j0..j0+63): 4 x 1KB
#pragma unroll
    for (int i = 0; i < 4; i++)
      GLOAD16(kg + (size_t)(j0 + i * 16) * 128, ksl + i * 512);
    // stage V dh-rows w*32..+31, both key panels: 4 x 1KB
#pragma unroll
    for (int i = 0; i < 2; i++) {
      GLOAD16(vg + (size_t)(i * 16) * Ss + j0,      vsl0 + i * 512);
      GLOAD16(vg + (size_t)(i * 16) * Ss + j0 + 32, vsl1 + i * 512);
    }
    __syncthreads();            // vmcnt(0) drained before use

    half32(j0, 0, &Vs[0]);                      // keys j0..j0+31
    if (j0 + 32 <= qrow_hi)                     // wave-uniform skip
      half32(j0 + 32, 2, &Vs[4096]);            // keys j0+32..j0+63
  }

  // reduce lsum over the 4 lg groups (same lm = same qrow)
  lsum += __shfl_xor(lsum, 16);
  lsum += __shfl_xor(lsum, 32);
  const float inv = 1.0f / lsum;

  // store: lane covers (qrow, dh = dt*16 + 4lg + 0..3)
  unsigned short* dst = attn + (size_t)(b * Ss + qrow) * Dd + h * DHd + lg * 4;
#pragma unroll
  for (int dt = 0; dt < 8; dt++) {
    ushort4 o4;
    o4.x = f2bf(ot[dt][0] * inv);
    o4.y = f2bf(ot[dt][1] * inv);
    o4.z = f2bf(ot[dt][2] * inv);
    o4.w = f2bf(ot[dt][3] * inv);
    *(ushort4*)(dst + dt * 16) = o4;
  }
}

// ---------------------------------------------------------------------------
extern "C" void kernel_launch(void* const* d_in, const int* in_sizes, int n_in,
                              void* d_out, int out_size, void* d_ws, size_t ws_size,
                              hipStream_t stream) {
  const float* x   = (const float*)d_in[0];   // (B,S,D)
  const float* qw  = (const float*)d_in[1];   // (2048, 2048)
  const float* qb  = (const float*)d_in[2];
  const float* kvw = (const float*)d_in[3];   // (256, 2048)
  const float* kvb = (const float*)d_in[4];
  const float* ow  = (const float*)d_in[5];   // (2048, 2048)
  const float* ob  = (const float*)d_in[6];
  float* out = (float*)d_out;

  // workspace layout (bf16 elements):
  //   wqkv @ 0          (2304 x 2048)   qw rows 0-2047, kvw 2048-2303
  //   owb  @ 4,718,592  (2048 x 2048)
  //   xb   @ 8,912,896  (4096 x 2048)   -> reused as attn_b
  //   QKV  @ 17,301,504 (4096 x 2304)
  //   Kb   @ 26,738,688 (4096 x 128)
  //   Vt   @ 27,262,976 (2 x 128 x 2048)
  //   ctab @ 27,787,264 (2048 x 64 float2 = 1 MB)
  unsigned short* wsb    = (unsigned short*)d_ws;
  unsigned short* wqkv   = wsb;
  unsigned short* owb    = wsb + 4718592;
  unsigned short* xb     = wsb + 8912896;
  unsigned short* attn_b = xb;                 // alias: xb dead after QKV gemm
  unsigned short* QKV    = wsb + 17301504;
  unsigned short* Kb     = wsb + 26738688;
  unsigned short* Vt     = wsb + 27262976;
  float2*         ctab   = (float2*)(wsb + 27787264);

  // 1. all fp32->bf16 casts + RoPE cos/sin table in one kernel
  cast_all<<<17408, 256, 0, stream>>>(qw, kvw, ow, x, wqkv, ctab);

  // 2. merged QKV projection: (4096 x 2304) = xb @ wqkv^T + [qb|kvb]
  gemm_bt_mfma<true><<<dim3(NQKV / TN, BS / TM), 256, 0, stream>>>(
      xb, wqkv, qb, kvb, 2048, QKV, BS, NQKV, Dd);

  // 3. K rope (table) + V transpose (Q rope fused into flash_v9)
  prep_kv<<<BS / 64, 256, 0, stream>>>(QKV, ctab, Kb, Vt);

  // 4. flash attention (balanced swizzle + conflict-free LDS + table Q-rope)
  flash_v9<<<1024, 256, 0, stream>>>(QKV, Kb, Vt, ctab, attn_b);

  // 5. O projection: out = attn @ ow^T + ob (fp32 out)
  gemm_bt_mfma<false><<<dim3(Dd / TN, BS / TM), 256, 0, stream>>>(
      attn_b, owb, ob, ob, Dd, out, BS, Dd, Dd);
}

// Round 5
// 307.835 us; speedup vs baseline: 1.2174x; 1.0322x over previous
//
#include <hip/hip_runtime.h>
#include <math.h>

// Problem constants (fixed by the reference)
constexpr int Bb  = 2;
constexpr int Ss  = 2048;
constexpr int Dd  = 2048;
constexpr int Hh  = 16;
constexpr int DHd = 128;
constexpr int BS  = Bb * Ss;   // 4096
constexpr int NQKV = 2304;     // 2048 q + 128 k + 128 v

typedef __bf16 bf16x8 __attribute__((ext_vector_type(8)));
typedef float  f32x4  __attribute__((ext_vector_type(4)));

// fp32 -> bf16 (RNE), bit-level
static __device__ __forceinline__ unsigned short f2bf(float f) {
  union { float f; unsigned int u; } a; a.f = f;
  unsigned int u = a.u;
  unsigned int r = (u + 0x7fffu + ((u >> 16) & 1u)) >> 16;
  return (unsigned short)r;
}
static __device__ __forceinline__ float bf2f(unsigned short u) {
  union { unsigned int u; float f; } a; a.u = ((unsigned int)u) << 16;
  return a.f;
}
// pack two fp32 -> one dword of 2 bf16 (lo = first)
static __device__ __forceinline__ int pk2bf(float lo, float hi) {
  return (int)((unsigned int)f2bf(lo) | ((unsigned int)f2bf(hi) << 16));
}
static __device__ __forceinline__ f32x4 mfma16(bf16x8 a, bf16x8 b, f32x4 c) {
  return __builtin_amdgcn_mfma_f32_16x16x32_bf16(a, b, c, 0, 0, 0);
}

// ---------------------------------------------------------------------------
// cast_all: blocks [0,16896): fp32 inputs -> bf16 into one contiguous region
//   [qw (2048x2048) | kvw (256x2048) | ow (2048x2048) | x (4096x2048)]
// blocks [16896,17408): fill RoPE cos/sin table ctab[s][i], s<2048, i<64.
// ---------------------------------------------------------------------------
__global__ __launch_bounds__(256) void cast_all(
    const float* __restrict__ qw, const float* __restrict__ kvw,
    const float* __restrict__ ow, const float* __restrict__ x,
    unsigned short* __restrict__ dst,
    float2* __restrict__ ctab)
{
  const int blk = blockIdx.x;
  if (blk >= 16896) {                              // RoPE table fill
    const int id = (blk - 16896) * 256 + threadIdx.x;  // 0..131071
    const int s = id >> 6, i = id & 63;
    const float invf = exp2f(-(float)i * (13.287712379549449f / 64.0f));
    const float ang = (float)s * invf;
    ctab[id] = make_float2(cosf(ang), sinf(ang));
    return;
  }
  const int i = blk * 256 + threadIdx.x;
  const float* src; int off;
  if (i < 1048576)      { src = qw;  off = 0; }
  else if (i < 1179648) { src = kvw; off = 1048576; }
  else if (i < 2228224) { src = ow;  off = 1179648; }
  else                  { src = x;   off = 2228224; }
  const float4 v = ((const float4*)src)[i - off];
  ushort4 o;
  o.x = f2bf(v.x); o.y = f2bf(v.y); o.z = f2bf(v.z); o.w = f2bf(v.w);
  ((ushort4*)dst)[i] = o;
}

// ---------------------------------------------------------------------------
// bf16 MFMA GEMM: C[M][N] = A[M][K] @ Bw[N][K]^T + bias(col).
// bias(col) = col < nsplit ? bias1[col] : bias2[col-nsplit]  (merged QKV).
// 128x128 tile, BK=32, 256 threads, global_load_lds width-16 staging.
// ---------------------------------------------------------------------------
#define TM 128
#define TN 128
#define TK 32

#define GLOAD16(gp, lp)                                                        \
  __builtin_amdgcn_global_load_lds(                                            \
      (const __attribute__((address_space(1))) void*)(gp),                     \
      (__attribute__((address_space(3))) void*)(lp), 16, 0, 0)

template <bool BF16OUT>
__global__ __launch_bounds__(256) void gemm_bt_mfma(
    const unsigned short* __restrict__ A,    // M x K bf16
    const unsigned short* __restrict__ Bw,   // N x K bf16
    const float* __restrict__ bias1,
    const float* __restrict__ bias2,
    int nsplit,
    void* __restrict__ Cv,                   // M x N (fp32 or bf16)
    int M, int N, int K)
{
  __shared__ unsigned short As[TM * TK];   // 8 KB
  __shared__ unsigned short Bs[TN * TK];   // 8 KB

  const int tid  = threadIdx.x;
  const int w    = tid >> 6;
  const int lane = tid & 63;
  const int m0   = blockIdx.y * TM;
  const int n0   = blockIdx.x * TN;
  const int wm   = (w >> 1) * 64;
  const int wn   = (w & 1) * 64;

  f32x4 acc[4][4];
#pragma unroll
  for (int i = 0; i < 4; i++)
#pragma unroll
    for (int j = 0; j < 4; j++) acc[i][j] = (f32x4){0.f, 0.f, 0.f, 0.f};

  const int srow = lane >> 2;
  const int scol = (lane & 3) * 8;
  const unsigned short* aG0 = A  + (size_t)(m0 +      w * 16 + srow) * K + scol;
  const unsigned short* aG1 = A  + (size_t)(m0 + 64 + w * 16 + srow) * K + scol;
  const unsigned short* bG0 = Bw + (size_t)(n0 +      w * 16 + srow) * K + scol;
  const unsigned short* bG1 = Bw + (size_t)(n0 + 64 + w * 16 + srow) * K + scol;
  unsigned short* aL0 = &As[(     w * 16) * TK];
  unsigned short* aL1 = &As[(64 + w * 16) * TK];
  unsigned short* bL0 = &Bs[(     w * 16) * TK];
  unsigned short* bL1 = &Bs[(64 + w * 16) * TK];

  const int fr = lane & 15;
  const int fk = (lane >> 4) * 8;

  for (int k0 = 0; k0 < K; k0 += TK) {
    __syncthreads();
    GLOAD16(aG0 + k0, aL0);
    GLOAD16(aG1 + k0, aL1);
    GLOAD16(bG0 + k0, bL0);
    GLOAD16(bG1 + k0, bL1);
    __syncthreads();

    bf16x8 af[4], bfr[4];
#pragma unroll
    for (int i = 0; i < 4; i++)
      af[i] = *(const bf16x8*)&As[(wm + i * 16 + fr) * TK + fk];
#pragma unroll
    for (int j = 0; j < 4; j++)
      bfr[j] = *(const bf16x8*)&Bs[(wn + j * 16 + fr) * TK + fk];
#pragma unroll
    for (int i = 0; i < 4; i++)
#pragma unroll
      for (int j = 0; j < 4; j++)
        acc[i][j] = mfma16(af[i], bfr[j], acc[i][j]);
  }

  const int er = (lane >> 4) * 4;
  const int ec = lane & 15;
#pragma unroll
  for (int j = 0; j < 4; j++) {
    const int col = n0 + wn + j * 16 + ec;
    const float bv = (col < nsplit) ? bias1[col] : bias2[col - nsplit];
#pragma unroll
    for (int i = 0; i < 4; i++) {
      const int rbase = m0 + wm + i * 16 + er;
#pragma unroll
      for (int r = 0; r < 4; r++) {
        const float v = acc[i][j][r] + bv;
        if constexpr (BF16OUT)
          ((unsigned short*)Cv)[(size_t)(rbase + r) * N + col] = f2bf(v);
        else
          ((float*)Cv)[(size_t)(rbase + r) * N + col] = v;
      }
    }
  }
}

// ---------------------------------------------------------------------------
// prep_kv: from QKV bf16 (B,S,2304) — k cols [2048,2176), v cols [2176,2304) —
// produce Kb (B,S,128) roped (table-driven) and Vt (B,128,S) transposed.
// ---------------------------------------------------------------------------
__global__ __launch_bounds__(256) void prep_kv(
    const unsigned short* __restrict__ QKV,
    const float2* __restrict__ ctab,
    unsigned short* __restrict__ Kb,
    unsigned short* __restrict__ Vt)
{
  __shared__ unsigned short Vtile[64 * 136];   // [s_local][d], padded

  const int blk = blockIdx.x;          // b*32 + stile
  const int b   = blk >> 5;
  const int s0  = (blk & 31) * 64;
  const int t   = threadIdx.x;

  // --- rope K (cos/sin from table)
  {
    const int r = t >> 2, p = t & 3;
    const int row = blk * 64 + r;
    const int s = row & (Ss - 1);
    const unsigned short* src = QKV + (size_t)row * NQKV + 2048 + p * 16;
    const float2* ct = ctab + s * 64 + p * 16;
    union { uint4 v[2]; unsigned short a[16]; } lo, hi, ol, oh;
    lo.v[0] = *(const uint4*)src;        lo.v[1] = *(const uint4*)(src + 8);
    hi.v[0] = *(const uint4*)(src + 64); hi.v[1] = *(const uint4*)(src + 72);
#pragma unroll
    for (int e = 0; e < 16; e++) {
      const float2 cs = ct[e];
      const float l = bf2f(lo.a[e]), hh = bf2f(hi.a[e]);
      ol.a[e] = f2bf(l * cs.x - hh * cs.y);
      oh.a[e] = f2bf(hh * cs.x + l * cs.y);
    }
    unsigned short* dst = Kb + (size_t)row * 128 + p * 16;
    *(uint4*)dst        = ol.v[0]; *(uint4*)(dst + 8)  = ol.v[1];
    *(uint4*)(dst + 64) = oh.v[0]; *(uint4*)(dst + 72) = oh.v[1];
  }

  // --- stage V into LDS, s-major
#pragma unroll
  for (int c = 0; c < 4; c++) {
    const int id = c * 256 + t;
    const int vr = id >> 4, cc = id & 15;
    *(uint4*)&Vtile[vr * 136 + cc * 8] =
        *(const uint4*)(QKV + (size_t)(blk * 64 + vr) * NQKV + 2176 + cc * 8);
  }
  __syncthreads();

  // --- write Vt rows
  {
    const int d = t >> 1, half = t & 1;
    union { uint4 v[4]; unsigned short a[32]; } val;
#pragma unroll
    for (int kk = 0; kk < 32; kk++)
      val.a[kk] = Vtile[(half * 32 + kk) * 136 + d];
    unsigned short* dst = Vt + ((size_t)(b * 128 + d)) * Ss + s0 + half * 32;
#pragma unroll
    for (int c = 0; c < 4; c++) *(uint4*)(dst + c * 8) = val.v[c];
  }
}

// ---------------------------------------------------------------------------
// flash_v10: causal MQA attention, PAIRED q-tiles (uniform-work blocks).
// Each block owns q-tiles qtA = 31-p (heavy) and qtB = p (light) for one
// (h,b). MQA => both consume the SAME K/V tiles, so one staging + one
// barrier-pair serves both. Per-block compute = 2(qtA+1)+2(qtB+1) = 66
// half32-units for EVERY block -> no within-CU tail (the v7-v9 structures
// measured 25% time-avg occupancy = tail-dominated makespan).
// Key tile = 128 (LDS 64 KB: K 4 panels [128 key x 32 dh], V 4 panels
// [128 dh x 32 key]); grid 512 = 2 blocks/CU, so 64 KB costs no residency.
// Co-resident blocks {c, c+256} get complementary p (equal iter counts).
// Conflict-free slot-XOR LDS + table-driven fused Q-rope as in v9.
// ---------------------------------------------------------------------------
__global__ __launch_bounds__(256, 2) void flash_v10(
    const unsigned short* __restrict__ QKV,  // (B,S,2304), q RAW (rope here)
    const unsigned short* __restrict__ Kb,   // (B,S,128) roped
    const unsigned short* __restrict__ Vt,   // (B,128,S)
    const float2* __restrict__ ctab,         // (2048, 64) cos/sin
    unsigned short* __restrict__ attn)       // (B,S,2048) bf16
{
  __shared__ unsigned short Ks[4 * 128 * 32];  // panel kf: [key128][dh32], 32 KB
  __shared__ unsigned short Vs[4 * 128 * 32];  // panel ks2: [dh128][key32], 32 KB

  // --- decode: co-resident {c, c+256} -> complementary p
  const int g  = (int)blockIdx.x;          // 0..511
  const int lo = g & 255, hi = g >> 8;
  const int p  = hi ? (15 - (lo & 15)) : (lo & 15);
  const int hb = (lo >> 4) + 16 * hi;      // 0..31
  const int h  = hb & 15;
  const int b  = hb >> 4;

  const int qA0 = (31 - p) * 64;           // heavy tile base (>= 1024)
  const int qB0 = p * 64;                  // light tile base (< 1024)

  const int tid = threadIdx.x;
  const int w = tid >> 6, lane = tid & 63;
  const int lg = lane >> 4, lm = lane & 15;
  const int qrowA = qA0 + w * 16 + lm;
  const int qrowA_hi = qA0 + w * 16 + 15;
  const int qrowB = qB0 + w * 16 + lm;
  const int qrowB_hi = qB0 + w * 16 + 15;

  // swizzled frag slot: row contributions >=16 vanish mod 4 -> lane-constant
  const int klg = lg ^ ((lm >> 1) & 3);

  // --- Q frags with fused table RoPE, for both tiles
  bf16x8 qfA[4], qfB[4];
  {
    union U8 { bf16x8 v; unsigned short a[8]; };
#pragma unroll
    for (int tile = 0; tile < 2; tile++) {
      const int qrow = tile ? qrowB : qrowA;
      const unsigned short* qp =
          QKV + (size_t)(b * Ss + qrow) * NQKV + h * DHd + lg * 8;
      const float2* ct = ctab + qrow * 64 + lg * 8;
      U8 lo0, lo1, hi0, hi1, ol0, ol1, oh0, oh1;
      lo0.v = *(const bf16x8*)(qp);
      lo1.v = *(const bf16x8*)(qp + 32);
      hi0.v = *(const bf16x8*)(qp + 64);
      hi1.v = *(const bf16x8*)(qp + 96);
#pragma unroll
      for (int j = 0; j < 8; j++) {
        {
          const float2 cs = ct[j];                      // i = lg*8+j
          const float l = bf2f(lo0.a[j]), hh = bf2f(hi0.a[j]);
          ol0.a[j] = f2bf(l * cs.x - hh * cs.y);
          oh0.a[j] = f2bf(hh * cs.x + l * cs.y);
        }
        {
          const float2 cs = ct[32 + j];                 // i = 32+lg*8+j
          const float l = bf2f(lo1.a[j]), hh = bf2f(hi1.a[j]);
          ol1.a[j] = f2bf(l * cs.x - hh * cs.y);
          oh1.a[j] = f2bf(hh * cs.x + l * cs.y);
        }
      }
      if (tile == 0) { qfA[0]=ol0.v; qfA[1]=ol1.v; qfA[2]=oh0.v; qfA[3]=oh1.v; }
      else           { qfB[0]=ol0.v; qfB[1]=ol1.v; qfB[2]=oh0.v; qfB[3]=oh1.v; }
    }
  }

  // O^T accumulators, C-layout: (dh = dt*16 + 4*lg + r, qrow = lm)
  f32x4 otA[8], otB[8];
#pragma unroll
  for (int dt = 0; dt < 8; dt++) {
    otA[dt] = (f32x4){0.f, 0.f, 0.f, 0.f};
    otB[dt] = (f32x4){0.f, 0.f, 0.f, 0.f};
  }
  float lsumA = 0.f, lsumB = 0.f;

  const float sscale = 0.08838834764831845f * 1.4426950408889634f; // /sqrt(128)*log2e

  // staging lane addresses; global chunk permuted so linear LDS dest holds
  // the slot-swizzled layout: chunk(lane) = (lane&3) ^ ((lane>>3)&3)
  const int sr  = lane >> 2;                             // row-within-16
  const int sc8 = ((lane & 3) ^ ((lane >> 3) & 3)) * 8;  // swizzled 16B chunk
  const unsigned short* kg =
      Kb + (size_t)b * Ss * 128 + (size_t)sr * 128 + w * 32 + sc8;
  const unsigned short* vg =
      Vt + (size_t)b * 128 * Ss + (size_t)(w * 32 + sr) * Ss + sc8;
  unsigned short* ksl = &Ks[w * 4096];      // panel w (dh w*32..+31), 128 keys

  // transpose shuffle sources (C->B layout, within a 32-key half)
  const int addr0 = (2 * (lg & 1)) * 16 + lm;   // dwords 0,1
  const int addr1 = addr0 + 16;                 // dwords 2,3
  const bool sel_hi = (lg & 2) != 0;

  // one 32-key half: S^T tiles tA,tA+1 -> exp -> transpose -> PV on panel VsP
  auto half32 = [&](int keybase, int tA, const unsigned short* VsP,
                    const bf16x8 (&qf)[4], f32x4 (&ot)[8], float& lsum,
                    int qrow) {
    f32x4 s[2];
    s[0] = (f32x4){0.f, 0.f, 0.f, 0.f};
    s[1] = (f32x4){0.f, 0.f, 0.f, 0.f};
#pragma unroll
    for (int kf = 0; kf < 4; kf++) {
      const bf16x8 k0 = *(const bf16x8*)&Ks[kf * 4096 + ((tA)     * 16 + lm) * 32 + klg * 8];
      const bf16x8 k1 = *(const bf16x8*)&Ks[kf * 4096 + ((tA + 1) * 16 + lm) * 32 + klg * 8];
      s[0] = mfma16(k0, qf[kf], s[0]);
      s[1] = mfma16(k1, qf[kf], s[1]);
    }
    // mask + exp2 (max-free) + pack
    int pk[2][2];
#pragma unroll
    for (int t = 0; t < 2; t++) {
      float pv[4];
#pragma unroll
      for (int r = 0; r < 4; r++) {
        const int key = keybase + t * 16 + 4 * lg + r;
        const float ev = exp2f(s[t][r] * sscale);
        pv[r] = (key <= qrow) ? ev : 0.f;
        lsum += pv[r];
      }
      pk[t][0] = pk2bf(pv[0], pv[1]);
      pk[t][1] = pk2bf(pv[2], pv[3]);
    }
    // C-layout -> B-layout transpose (8 bpermutes)
    union { int d[4]; bf16x8 v; } pb;
#pragma unroll
    for (int d = 0; d < 4; d++) {
      const int src = (d < 2) ? addr0 : addr1;
      const int v0 = __shfl(pk[0][d & 1], src);
      const int v1 = __shfl(pk[1][d & 1], src);
      pb.d[d] = sel_hi ? v1 : v0;
    }
    // O^T += V^T(32 keys) · P^T
#pragma unroll
    for (int dt = 0; dt < 8; dt++) {
      const bf16x8 vfrag = *(const bf16x8*)&VsP[(dt * 16 + lm) * 32 + klg * 8];
      ot[dt] = mfma16(vfrag, pb.v, ot[dt]);
    }
  };

  for (int j0 = 0; j0 <= qA0; j0 += 128) {
    __syncthreads();            // previous iteration's LDS readers done
    // stage K panel w (dh w*32..+31, keys j0..j0+127): 8 x 1KB
#pragma unroll
    for (int i = 0; i < 8; i++)
      GLOAD16(kg + (size_t)(j0 + i * 16) * 128, ksl + i * 512);
    // stage V dh-rows w*32..+31, 4 key panels: 8 x 1KB
#pragma unroll
    for (int ks2 = 0; ks2 < 4; ks2++) {
      unsigned short* vsl = &Vs[ks2 * 4096 + (w * 32) * 32];
      GLOAD16(vg + j0 + ks2 * 32,                  vsl);
      GLOAD16(vg + (size_t)16 * Ss + j0 + ks2 * 32, vsl + 512);
    }
    __syncthreads();            // vmcnt(0) drained before use

    // --- tile A (heavy): up to 4 half32s
    half32(j0, 0, &Vs[0], qfA, otA, lsumA, qrowA);
    if (j0 + 32 <= qrowA_hi)
      half32(j0 + 32, 2, &Vs[4096], qfA, otA, lsumA, qrowA);
    if (j0 + 64 <= qA0) {       // second 64-key subtile exists for A
      half32(j0 + 64, 4, &Vs[8192], qfA, otA, lsumA, qrowA);
      if (j0 + 96 <= qrowA_hi)
        half32(j0 + 96, 6, &Vs[12288], qfA, otA, lsumA, qrowA);
    }
    // --- tile B (light): same staged K/V (MQA)
    if (j0 <= qB0) {
      half32(j0, 0, &Vs[0], qfB, otB, lsumB, qrowB);
      if (j0 + 32 <= qrowB_hi)
        half32(j0 + 32, 2, &Vs[4096], qfB, otB, lsumB, qrowB);
      if (j0 + 64 <= qB0) {
        half32(j0 + 64, 4, &Vs[8192], qfB, otB, lsumB, qrowB);
        if (j0 + 96 <= qrowB_hi)
          half32(j0 + 96, 6, &Vs[12288], qfB, otB, lsumB, qrowB);
      }
    }
  }

  // --- epilogue x2: reduce lsum over the 4 lg groups, normalize, store
#pragma unroll
  for (int tile = 0; tile < 2; tile++) {
    float lsum = tile ? lsumB : lsumA;
    const int qrow = tile ? qrowB : qrowA;
    lsum += __shfl_xor(lsum, 16);
    lsum += __shfl_xor(lsum, 32);
    const float inv = 1.0f / lsum;
    unsigned short* dst =
        attn + (size_t)(b * Ss + qrow) * Dd + h * DHd + lg * 4;
#pragma unroll
    for (int dt = 0; dt < 8; dt++) {
      const f32x4 o = tile ? otB[dt] : otA[dt];
      ushort4 o4;
      o4.x = f2bf(o[0] * inv);
      o4.y = f2bf(o[1] * inv);
      o4.z = f2bf(o[2] * inv);
      o4.w = f2bf(o[3] * inv);
      *(ushort4*)(dst + dt * 16) = o4;
    }
  }
}

// ---------------------------------------------------------------------------
extern "C" void kernel_launch(void* const* d_in, const int* in_sizes, int n_in,
                              void* d_out, int out_size, void* d_ws, size_t ws_size,
                              hipStream_t stream) {
  const float* x   = (const float*)d_in[0];   // (B,S,D)
  const float* qw  = (const float*)d_in[1];   // (2048, 2048)
  const float* qb  = (const float*)d_in[2];
  const float* kvw = (const float*)d_in[3];   // (256, 2048)
  const float* kvb = (const float*)d_in[4];
  const float* ow  = (const float*)d_in[5];   // (2048, 2048)
  const float* ob  = (const float*)d_in[6];
  float* out = (float*)d_out;

  // workspace layout (bf16 elements):
  //   wqkv @ 0          (2304 x 2048)   qw rows 0-2047, kvw 2048-2303
  //   owb  @ 4,718,592  (2048 x 2048)
  //   xb   @ 8,912,896  (4096 x 2048)   -> reused as attn_b
  //   QKV  @ 17,301,504 (4096 x 2304)
  //   Kb   @ 26,738,688 (4096 x 128)
  //   Vt   @ 27,262,976 (2 x 128 x 2048)
  //   ctab @ 27,787,264 (2048 x 64 float2 = 1 MB)
  unsigned short* wsb    = (unsigned short*)d_ws;
  unsigned short* wqkv   = wsb;
  unsigned short* owb    = wsb + 4718592;
  unsigned short* xb     = wsb + 8912896;
  unsigned short* attn_b = xb;                 // alias: xb dead after QKV gemm
  unsigned short* QKV    = wsb + 17301504;
  unsigned short* Kb     = wsb + 26738688;
  unsigned short* Vt     = wsb + 27262976;
  float2*         ctab   = (float2*)(wsb + 27787264);

  // 1. all fp32->bf16 casts + RoPE cos/sin table in one kernel
  cast_all<<<17408, 256, 0, stream>>>(qw, kvw, ow, x, wqkv, ctab);

  // 2. merged QKV projection: (4096 x 2304) = xb @ wqkv^T + [qb|kvb]
  gemm_bt_mfma<true><<<dim3(NQKV / TN, BS / TM), 256, 0, stream>>>(
      xb, wqkv, qb, kvb, 2048, QKV, BS, NQKV, Dd);

  // 3. K rope (table) + V transpose (Q rope fused into flash_v10)
  prep_kv<<<BS / 64, 256, 0, stream>>>(QKV, ctab, Kb, Vt);

  // 4. flash attention (paired q-tiles, uniform-work blocks, 128-key tiles)
  flash_v10<<<512, 256, 0, stream>>>(QKV, Kb, Vt, ctab, attn_b);

  // 5. O projection: out = attn @ ow^T + ob (fp32 out)
  gemm_bt_mfma<false><<<dim3(Dd / TN, BS / TM), 256, 0, stream>>>(
      attn_b, owb, ob, ob, Dd, out, BS, Dd, Dd);
}

// Round 6
// 304.325 us; speedup vs baseline: 1.2314x; 1.0115x over previous
//
#include <hip/hip_runtime.h>
#include <math.h>

// Problem constants (fixed by the reference)
constexpr int Bb  = 2;
constexpr int Ss  = 2048;
constexpr int Dd  = 2048;
constexpr int Hh  = 16;
constexpr int DHd = 128;
constexpr int BS  = Bb * Ss;   // 4096
constexpr int NQKV = 2304;     // 2048 q + 128 k + 128 v

typedef __bf16 bf16x8 __attribute__((ext_vector_type(8)));
typedef float  f32x4  __attribute__((ext_vector_type(4)));

// fp32 -> bf16 (RNE), bit-level
static __device__ __forceinline__ unsigned short f2bf(float f) {
  union { float f; unsigned int u; } a; a.f = f;
  unsigned int u = a.u;
  unsigned int r = (u + 0x7fffu + ((u >> 16) & 1u)) >> 16;
  return (unsigned short)r;
}
static __device__ __forceinline__ float bf2f(unsigned short u) {
  union { unsigned int u; float f; } a; a.u = ((unsigned int)u) << 16;
  return a.f;
}
// pack two fp32 -> one dword of 2 bf16 (lo = first), HW RNE pack
static __device__ __forceinline__ int cvtpk(float lo, float hi) {
  int r;
  asm("v_cvt_pk_bf16_f32 %0, %1, %2" : "=v"(r) : "v"(lo), "v"(hi));
  return r;
}
static __device__ __forceinline__ f32x4 mfma16(bf16x8 a, bf16x8 b, f32x4 c) {
  return __builtin_amdgcn_mfma_f32_16x16x32_bf16(a, b, c, 0, 0, 0);
}

// ---------------------------------------------------------------------------
// cast_all: blocks [0,16896): fp32 inputs -> bf16 into one contiguous region
//   [qw (2048x2048) | kvw (256x2048) | ow (2048x2048) | x (4096x2048)]
// blocks [16896,17408): fill RoPE cos/sin table ctab[s][i], s<2048, i<64.
// ---------------------------------------------------------------------------
__global__ __launch_bounds__(256) void cast_all(
    const float* __restrict__ qw, const float* __restrict__ kvw,
    const float* __restrict__ ow, const float* __restrict__ x,
    unsigned short* __restrict__ dst,
    float2* __restrict__ ctab)
{
  const int blk = blockIdx.x;
  if (blk >= 16896) {                              // RoPE table fill
    const int id = (blk - 16896) * 256 + threadIdx.x;  // 0..131071
    const int s = id >> 6, i = id & 63;
    const float invf = exp2f(-(float)i * (13.287712379549449f / 64.0f));
    const float ang = (float)s * invf;
    ctab[id] = make_float2(cosf(ang), sinf(ang));
    return;
  }
  const int i = blk * 256 + threadIdx.x;
  const float* src; int off;
  if (i < 1048576)      { src = qw;  off = 0; }
  else if (i < 1179648) { src = kvw; off = 1048576; }
  else if (i < 2228224) { src = ow;  off = 1179648; }
  else                  { src = x;   off = 2228224; }
  const float4 v = ((const float4*)src)[i - off];
  ushort4 o;
  o.x = f2bf(v.x); o.y = f2bf(v.y); o.z = f2bf(v.z); o.w = f2bf(v.w);
  ((ushort4*)dst)[i] = o;
}

// ---------------------------------------------------------------------------
// bf16 MFMA GEMM: C[M][N] = A[M][K] @ Bw[N][K]^T + bias(col).
// bias(col) = col < nsplit ? bias1[col] : bias2[col-nsplit]  (merged QKV).
// 128x128 tile, BK=32, 256 threads, global_load_lds width-16 staging.
// ---------------------------------------------------------------------------
#define TM 128
#define TN 128
#define TK 32

#define GLOAD16(gp, lp)                                                        \
  __builtin_amdgcn_global_load_lds(                                            \
      (const __attribute__((address_space(1))) void*)(gp),                     \
      (__attribute__((address_space(3))) void*)(lp), 16, 0, 0)

template <bool BF16OUT>
__global__ __launch_bounds__(256) void gemm_bt_mfma(
    const unsigned short* __restrict__ A,    // M x K bf16
    const unsigned short* __restrict__ Bw,   // N x K bf16
    const float* __restrict__ bias1,
    const float* __restrict__ bias2,
    int nsplit,
    void* __restrict__ Cv,                   // M x N (fp32 or bf16)
    int M, int N, int K)
{
  __shared__ unsigned short As[TM * TK];   // 8 KB
  __shared__ unsigned short Bs[TN * TK];   // 8 KB

  const int tid  = threadIdx.x;
  const int w    = tid >> 6;
  const int lane = tid & 63;
  const int m0   = blockIdx.y * TM;
  const int n0   = blockIdx.x * TN;
  const int wm   = (w >> 1) * 64;
  const int wn   = (w & 1) * 64;

  f32x4 acc[4][4];
#pragma unroll
  for (int i = 0; i < 4; i++)
#pragma unroll
    for (int j = 0; j < 4; j++) acc[i][j] = (f32x4){0.f, 0.f, 0.f, 0.f};

  const int srow = lane >> 2;
  const int scol = (lane & 3) * 8;
  const unsigned short* aG0 = A  + (size_t)(m0 +      w * 16 + srow) * K + scol;
  const unsigned short* aG1 = A  + (size_t)(m0 + 64 + w * 16 + srow) * K + scol;
  const unsigned short* bG0 = Bw + (size_t)(n0 +      w * 16 + srow) * K + scol;
  const unsigned short* bG1 = Bw + (size_t)(n0 + 64 + w * 16 + srow) * K + scol;
  unsigned short* aL0 = &As[(     w * 16) * TK];
  unsigned short* aL1 = &As[(64 + w * 16) * TK];
  unsigned short* bL0 = &Bs[(     w * 16) * TK];
  unsigned short* bL1 = &Bs[(64 + w * 16) * TK];

  const int fr = lane & 15;
  const int fk = (lane >> 4) * 8;

  for (int k0 = 0; k0 < K; k0 += TK) {
    __syncthreads();
    GLOAD16(aG0 + k0, aL0);
    GLOAD16(aG1 + k0, aL1);
    GLOAD16(bG0 + k0, bL0);
    GLOAD16(bG1 + k0, bL1);
    __syncthreads();

    bf16x8 af[4], bfr[4];
#pragma unroll
    for (int i = 0; i < 4; i++)
      af[i] = *(const bf16x8*)&As[(wm + i * 16 + fr) * TK + fk];
#pragma unroll
    for (int j = 0; j < 4; j++)
      bfr[j] = *(const bf16x8*)&Bs[(wn + j * 16 + fr) * TK + fk];
#pragma unroll
    for (int i = 0; i < 4; i++)
#pragma unroll
      for (int j = 0; j < 4; j++)
        acc[i][j] = mfma16(af[i], bfr[j], acc[i][j]);
  }

  const int er = (lane >> 4) * 4;
  const int ec = lane & 15;
#pragma unroll
  for (int j = 0; j < 4; j++) {
    const int col = n0 + wn + j * 16 + ec;
    const float bv = (col < nsplit) ? bias1[col] : bias2[col - nsplit];
#pragma unroll
    for (int i = 0; i < 4; i++) {
      const int rbase = m0 + wm + i * 16 + er;
#pragma unroll
      for (int r = 0; r < 4; r++) {
        const float v = acc[i][j][r] + bv;
        if constexpr (BF16OUT)
          ((unsigned short*)Cv)[(size_t)(rbase + r) * N + col] = f2bf(v);
        else
          ((float*)Cv)[(size_t)(rbase + r) * N + col] = v;
      }
    }
  }
}

// ---------------------------------------------------------------------------
// prep_kv: from QKV bf16 (B,S,2304) — k cols [2048,2176), v cols [2176,2304) —
// produce Kb (B,S,128) roped (table-driven) and Vt (B,128,S) transposed.
// ---------------------------------------------------------------------------
__global__ __launch_bounds__(256) void prep_kv(
    const unsigned short* __restrict__ QKV,
    const float2* __restrict__ ctab,
    unsigned short* __restrict__ Kb,
    unsigned short* __restrict__ Vt)
{
  __shared__ unsigned short Vtile[64 * 136];   // [s_local][d], padded

  const int blk = blockIdx.x;          // b*32 + stile
  const int b   = blk >> 5;
  const int s0  = (blk & 31) * 64;
  const int t   = threadIdx.x;

  // --- rope K (cos/sin from table)
  {
    const int r = t >> 2, p = t & 3;
    const int row = blk * 64 + r;
    const int s = row & (Ss - 1);
    const unsigned short* src = QKV + (size_t)row * NQKV + 2048 + p * 16;
    const float2* ct = ctab + s * 64 + p * 16;
    union { uint4 v[2]; unsigned short a[16]; } lo, hi, ol, oh;
    lo.v[0] = *(const uint4*)src;        lo.v[1] = *(const uint4*)(src + 8);
    hi.v[0] = *(const uint4*)(src + 64); hi.v[1] = *(const uint4*)(src + 72);
#pragma unroll
    for (int e = 0; e < 16; e++) {
      const float2 cs = ct[e];
      const float l = bf2f(lo.a[e]), hh = bf2f(hi.a[e]);
      ol.a[e] = f2bf(l * cs.x - hh * cs.y);
      oh.a[e] = f2bf(hh * cs.x + l * cs.y);
    }
    unsigned short* dst = Kb + (size_t)row * 128 + p * 16;
    *(uint4*)dst        = ol.v[0]; *(uint4*)(dst + 8)  = ol.v[1];
    *(uint4*)(dst + 64) = oh.v[0]; *(uint4*)(dst + 72) = oh.v[1];
  }

  // --- stage V into LDS, s-major
#pragma unroll
  for (int c = 0; c < 4; c++) {
    const int id = c * 256 + t;
    const int vr = id >> 4, cc = id & 15;
    *(uint4*)&Vtile[vr * 136 + cc * 8] =
        *(const uint4*)(QKV + (size_t)(blk * 64 + vr) * NQKV + 2176 + cc * 8);
  }
  __syncthreads();

  // --- write Vt rows
  {
    const int d = t >> 1, half = t & 1;
    union { uint4 v[4]; unsigned short a[32]; } val;
#pragma unroll
    for (int kk = 0; kk < 32; kk++)
      val.a[kk] = Vtile[(half * 32 + kk) * 136 + d];
    unsigned short* dst = Vt + ((size_t)(b * 128 + d)) * Ss + s0 + half * 32;
#pragma unroll
    for (int c = 0; c < 4; c++) *(uint4*)(dst + c * 8) = val.v[c];
  }
}

// ---------------------------------------------------------------------------
// flash_v11: v10 (paired q-tiles, uniform-work blocks, 128-key tiles) with the
// softmax VALU diet (VALUBusy was 43.5% = 2.5x the MFMA time):
//  - sscale folded into Q at the rope prologue (no per-half32 v_mul, exp2f(s))
//  - v_cvt_pk_bf16_f32 replaces the bit-twiddled bf16 pack (softmax + store)
//  - causal cmp/cndmask only on diagonal subtiles (wave-uniform needmask)
//  - s_setprio(1) around the QK / PV MFMA clusters (T5)
// ---------------------------------------------------------------------------
__global__ __launch_bounds__(256, 2) void flash_v11(
    const unsigned short* __restrict__ QKV,  // (B,S,2304), q RAW (rope here)
    const unsigned short* __restrict__ Kb,   // (B,S,128) roped
    const unsigned short* __restrict__ Vt,   // (B,128,S)
    const float2* __restrict__ ctab,         // (2048, 64) cos/sin
    unsigned short* __restrict__ attn)       // (B,S,2048) bf16
{
  __shared__ unsigned short Ks[4 * 128 * 32];  // panel kf: [key128][dh32], 32 KB
  __shared__ unsigned short Vs[4 * 128 * 32];  // panel ks2: [dh128][key32], 32 KB

  // --- decode: co-resident {c, c+256} -> complementary p
  const int g  = (int)blockIdx.x;          // 0..511
  const int lo = g & 255, hi = g >> 8;
  const int p  = hi ? (15 - (lo & 15)) : (lo & 15);
  const int hb = (lo >> 4) + 16 * hi;      // 0..31
  const int h  = hb & 15;
  const int b  = hb >> 4;

  const int qA0 = (31 - p) * 64;           // heavy tile base (>= 1024)
  const int qB0 = p * 64;                  // light tile base (< 1024)

  const int tid = threadIdx.x;
  const int w = tid >> 6, lane = tid & 63;
  const int lg = lane >> 4, lm = lane & 15;
  const int qrowA = qA0 + w * 16 + lm;
  const int qrowA_lo = qA0 + w * 16;
  const int qrowA_hi = qA0 + w * 16 + 15;
  const int qrowB = qB0 + w * 16 + lm;
  const int qrowB_lo = qB0 + w * 16;
  const int qrowB_hi = qB0 + w * 16 + 15;

  // swizzled frag slot: row contributions >=16 vanish mod 4 -> lane-constant
  const int klg = lg ^ ((lm >> 1) & 3);

  const float sscale = 0.08838834764831845f * 1.4426950408889634f; // /sqrt(128)*log2e

  // --- Q frags with fused table RoPE, PRE-SCALED by sscale (both tiles).
  // bf16 rounding count identical to unscaled version -> same error profile.
  bf16x8 qfA[4], qfB[4];
  {
    union U8 { bf16x8 v; unsigned short a[8]; };
#pragma unroll
    for (int tile = 0; tile < 2; tile++) {
      const int qrow = tile ? qrowB : qrowA;
      const unsigned short* qp =
          QKV + (size_t)(b * Ss + qrow) * NQKV + h * DHd + lg * 8;
      const float2* ct = ctab + qrow * 64 + lg * 8;
      U8 lo0, lo1, hi0, hi1, ol0, ol1, oh0, oh1;
      lo0.v = *(const bf16x8*)(qp);
      lo1.v = *(const bf16x8*)(qp + 32);
      hi0.v = *(const bf16x8*)(qp + 64);
      hi1.v = *(const bf16x8*)(qp + 96);
#pragma unroll
      for (int j = 0; j < 8; j++) {
        {
          const float2 cs = ct[j];                      // i = lg*8+j
          const float l = bf2f(lo0.a[j]), hh = bf2f(hi0.a[j]);
          ol0.a[j] = f2bf((l * cs.x - hh * cs.y) * sscale);
          oh0.a[j] = f2bf((hh * cs.x + l * cs.y) * sscale);
        }
        {
          const float2 cs = ct[32 + j];                 // i = 32+lg*8+j
          const float l = bf2f(lo1.a[j]), hh = bf2f(hi1.a[j]);
          ol1.a[j] = f2bf((l * cs.x - hh * cs.y) * sscale);
          oh1.a[j] = f2bf((hh * cs.x + l * cs.y) * sscale);
        }
      }
      if (tile == 0) { qfA[0]=ol0.v; qfA[1]=ol1.v; qfA[2]=oh0.v; qfA[3]=oh1.v; }
      else           { qfB[0]=ol0.v; qfB[1]=ol1.v; qfB[2]=oh0.v; qfB[3]=oh1.v; }
    }
  }

  // O^T accumulators, C-layout: (dh = dt*16 + 4*lg + r, qrow = lm)
  f32x4 otA[8], otB[8];
#pragma unroll
  for (int dt = 0; dt < 8; dt++) {
    otA[dt] = (f32x4){0.f, 0.f, 0.f, 0.f};
    otB[dt] = (f32x4){0.f, 0.f, 0.f, 0.f};
  }
  float lsumA = 0.f, lsumB = 0.f;

  // staging lane addresses; global chunk permuted so linear LDS dest holds
  // the slot-swizzled layout: chunk(lane) = (lane&3) ^ ((lane>>3)&3)
  const int sr  = lane >> 2;                             // row-within-16
  const int sc8 = ((lane & 3) ^ ((lane >> 3) & 3)) * 8;  // swizzled 16B chunk
  const unsigned short* kg =
      Kb + (size_t)b * Ss * 128 + (size_t)sr * 128 + w * 32 + sc8;
  const unsigned short* vg =
      Vt + (size_t)b * 128 * Ss + (size_t)(w * 32 + sr) * Ss + sc8;
  unsigned short* ksl = &Ks[w * 4096];      // panel w (dh w*32..+31), 128 keys

  // transpose shuffle sources (C->B layout, within a 32-key half)
  const int addr0 = (2 * (lg & 1)) * 16 + lm;   // dwords 0,1
  const int addr1 = addr0 + 16;                 // dwords 2,3
  const bool sel_hi = (lg & 2) != 0;

  // one 32-key half: S^T tiles tA,tA+1 -> exp -> transpose -> PV on panel VsP
  auto half32 = [&](int keybase, int tA, const unsigned short* VsP,
                    const bf16x8 (&qf)[4], f32x4 (&ot)[8], float& lsum,
                    int qrow, bool needmask) {
    f32x4 s[2];
    s[0] = (f32x4){0.f, 0.f, 0.f, 0.f};
    s[1] = (f32x4){0.f, 0.f, 0.f, 0.f};
    __builtin_amdgcn_s_setprio(1);
#pragma unroll
    for (int kf = 0; kf < 4; kf++) {
      const bf16x8 k0 = *(const bf16x8*)&Ks[kf * 4096 + ((tA)     * 16 + lm) * 32 + klg * 8];
      const bf16x8 k1 = *(const bf16x8*)&Ks[kf * 4096 + ((tA + 1) * 16 + lm) * 32 + klg * 8];
      s[0] = mfma16(k0, qf[kf], s[0]);
      s[1] = mfma16(k1, qf[kf], s[1]);
    }
    __builtin_amdgcn_s_setprio(0);
    // exp2 (max-free, Q pre-scaled) + diagonal-only mask + pack
    int pk[2][2];
#pragma unroll
    for (int t = 0; t < 2; t++) {
      float pv[4];
#pragma unroll
      for (int r = 0; r < 4; r++) pv[r] = exp2f(s[t][r]);
      if (needmask) {
        const int kb = keybase + t * 16 + 4 * lg;
#pragma unroll
        for (int r = 0; r < 4; r++)
          if (kb + r > qrow) pv[r] = 0.f;
      }
#pragma unroll
      for (int r = 0; r < 4; r++) lsum += pv[r];
      pk[t][0] = cvtpk(pv[0], pv[1]);
      pk[t][1] = cvtpk(pv[2], pv[3]);
    }
    // C-layout -> B-layout transpose (8 bpermutes)
    union { int d[4]; bf16x8 v; } pb;
#pragma unroll
    for (int d = 0; d < 4; d++) {
      const int src = (d < 2) ? addr0 : addr1;
      const int v0 = __shfl(pk[0][d & 1], src);
      const int v1 = __shfl(pk[1][d & 1], src);
      pb.d[d] = sel_hi ? v1 : v0;
    }
    // O^T += V^T(32 keys) · P^T
    __builtin_amdgcn_s_setprio(1);
#pragma unroll
    for (int dt = 0; dt < 8; dt++) {
      const bf16x8 vfrag = *(const bf16x8*)&VsP[(dt * 16 + lm) * 32 + klg * 8];
      ot[dt] = mfma16(vfrag, pb.v, ot[dt]);
    }
    __builtin_amdgcn_s_setprio(0);
  };

  for (int j0 = 0; j0 <= qA0; j0 += 128) {
    __syncthreads();            // previous iteration's LDS readers done
    // stage K panel w (dh w*32..+31, keys j0..j0+127): 8 x 1KB
#pragma unroll
    for (int i = 0; i < 8; i++)
      GLOAD16(kg + (size_t)(j0 + i * 16) * 128, ksl + i * 512);
    // stage V dh-rows w*32..+31, 4 key panels: 8 x 1KB
#pragma unroll
    for (int ks2 = 0; ks2 < 4; ks2++) {
      unsigned short* vsl = &Vs[ks2 * 4096 + (w * 32) * 32];
      GLOAD16(vg + j0 + ks2 * 32,                  vsl);
      GLOAD16(vg + (size_t)16 * Ss + j0 + ks2 * 32, vsl + 512);
    }
    __syncthreads();            // vmcnt(0) drained before use

    // --- tile A (heavy): subtile runs iff keybase <= qrowA_hi
#pragma unroll
    for (int t32 = 0; t32 < 4; t32++) {
      const int kb = j0 + t32 * 32;
      if (kb <= qrowA_hi)
        half32(kb, t32 * 2, &Vs[t32 * 4096], qfA, otA, lsumA, qrowA,
               kb + 31 > qrowA_lo);
    }
    // --- tile B (light): same staged K/V (MQA)
#pragma unroll
    for (int t32 = 0; t32 < 4; t32++) {
      const int kb = j0 + t32 * 32;
      if (kb <= qrowB_hi)
        half32(kb, t32 * 2, &Vs[t32 * 4096], qfB, otB, lsumB, qrowB,
               kb + 31 > qrowB_lo);
    }
  }

  // --- epilogue x2: reduce lsum over the 4 lg groups, normalize, store
#pragma unroll
  for (int tile = 0; tile < 2; tile++) {
    float lsum = tile ? lsumB : lsumA;
    const int qrow = tile ? qrowB : qrowA;
    lsum += __shfl_xor(lsum, 16);
    lsum += __shfl_xor(lsum, 32);
    const float inv = 1.0f / lsum;
    unsigned short* dst =
        attn + (size_t)(b * Ss + qrow) * Dd + h * DHd + lg * 4;
#pragma unroll
    for (int dt = 0; dt < 8; dt++) {
      const f32x4 o = tile ? otB[dt] : otA[dt];
      uint2 st;
      st.x = (unsigned int)cvtpk(o[0] * inv, o[1] * inv);
      st.y = (unsigned int)cvtpk(o[2] * inv, o[3] * inv);
      *(uint2*)(dst + dt * 16) = st;
    }
  }
}

// ---------------------------------------------------------------------------
extern "C" void kernel_launch(void* const* d_in, const int* in_sizes, int n_in,
                              void* d_out, int out_size, void* d_ws, size_t ws_size,
                              hipStream_t stream) {
  const float* x   = (const float*)d_in[0];   // (B,S,D)
  const float* qw  = (const float*)d_in[1];   // (2048, 2048)
  const float* qb  = (const float*)d_in[2];
  const float* kvw = (const float*)d_in[3];   // (256, 2048)
  const float* kvb = (const float*)d_in[4];
  const float* ow  = (const float*)d_in[5];   // (2048, 2048)
  const float* ob  = (const float*)d_in[6];
  float* out = (float*)d_out;

  // workspace layout (bf16 elements):
  //   wqkv @ 0          (2304 x 2048)   qw rows 0-2047, kvw 2048-2303
  //   owb  @ 4,718,592  (2048 x 2048)
  //   xb   @ 8,912,896  (4096 x 2048)   -> reused as attn_b
  //   QKV  @ 17,301,504 (4096 x 2304)
  //   Kb   @ 26,738,688 (4096 x 128)
  //   Vt   @ 27,262,976 (2 x 128 x 2048)
  //   ctab @ 27,787,264 (2048 x 64 float2 = 1 MB)
  unsigned short* wsb    = (unsigned short*)d_ws;
  unsigned short* wqkv   = wsb;
  unsigned short* owb    = wsb + 4718592;
  unsigned short* xb     = wsb + 8912896;
  unsigned short* attn_b = xb;                 // alias: xb dead after QKV gemm
  unsigned short* QKV    = wsb + 17301504;
  unsigned short* Kb     = wsb + 26738688;
  unsigned short* Vt     = wsb + 27262976;
  float2*         ctab   = (float2*)(wsb + 27787264);

  // 1. all fp32->bf16 casts + RoPE cos/sin table in one kernel
  cast_all<<<17408, 256, 0, stream>>>(qw, kvw, ow, x, wqkv, ctab);

  // 2. merged QKV projection: (4096 x 2304) = xb @ wqkv^T + [qb|kvb]
  gemm_bt_mfma<true><<<dim3(NQKV / TN, BS / TM), 256, 0, stream>>>(
      xb, wqkv, qb, kvb, 2048, QKV, BS, NQKV, Dd);

  // 3. K rope (table) + V transpose (Q rope fused into flash_v11)
  prep_kv<<<BS / 64, 256, 0, stream>>>(QKV, ctab, Kb, Vt);

  // 4. flash attention (paired q-tiles + softmax VALU diet)
  flash_v11<<<512, 256, 0, stream>>>(QKV, Kb, Vt, ctab, attn_b);

  // 5. O projection: out = attn @ ow^T + ob (fp32 out)
  gemm_bt_mfma<false><<<dim3(Dd / TN, BS / TM), 256, 0, stream>>>(
      attn_b, owb, ob, ob, Dd, out, BS, Dd, Dd);
}